// Round 4
// baseline (1767.673 us; speedup 1.0000x reference)
//
#include <hip/hip_runtime.h>

// ---------------- problem constants ----------------
constexpr int N = 100000;
constexpr int F = 512;
constexpr int H = 128;
constexpr int E = 1600000;
constexpr int C = 64;
constexpr float EPS = 1e-5f;
constexpr float NF = 100000.0f;     // number of nodes as float
constexpr float IBN = 0.999995000037f; // 1/sqrt(1+1e-5)

// ---------------- workspace layout (float offsets) ----------------
constexpr size_t OFF_HT   = 0;                     // [N,H] trans hidden, later x1 (in-place)
constexpr size_t OFF_HG   = 12800000;              // [N,H] graph hidden, later x2 (in-place)
constexpr size_t OFF_AGG  = 25600000;              // [N,H] gather target
constexpr size_t OFF_CNT  = 38400000;              // int[N] in-degree
constexpr size_t OFF_GP   = 38500000;              // 8 x [128,128] gram partials
constexpr size_t OFF_S    = 38631072;              // [128] colsum
constexpr size_t ZERO_BEGIN = OFF_CNT;
constexpr size_t ZERO_COUNT = (OFF_S + 128) - OFF_CNT;  // cnt + GP + s
constexpr size_t OFF_G    = 38631200;              // [128,128] gram (written by reduce)
constexpr size_t OFF_PTR  = 38647584;              // int[N] CSR bucket starts
constexpr size_t OFF_CUR  = 38747584;              // int[N] placement cursors
constexpr size_t OFF_BS   = 38847584;              // int[128] scan block offsets
constexpr size_t OFF_SROW = 38847712;              // int[E] sorted src rows
constexpr size_t OFF_SVAL = 40447712;              // float[E] sorted edge weights
constexpr size_t OFF_GWV  = 42047712;              // 3 x [128,256]: G@Wv, G@Wk, G@Wq
constexpr size_t OFF_KV   = OFF_GWV + 3 * 32768;   // [2,128,128] kv_raw
constexpr size_t OFF_KSUM = OFF_KV + 32768;        // [256]
constexpr size_t OFF_VSUM = OFF_KSUM + 256;        // [256]
constexpr size_t OFF_QSUM = OFF_VSUM + 256;        // [256]
constexpr size_t OFF_SC   = OFF_QSUM + 256;        // [4]
constexpr size_t OFF_B    = OFF_SC + 4;            // [128,256]
constexpr size_t OFF_CC   = OFF_B + 32768;         // [256]
constexpr size_t OFF_U    = OFF_CC + 256;          // [128,2]
constexpr size_t OFF_U0   = OFF_U + 256;           // [2]
constexpr size_t OFF_BT   = OFF_U0 + 4;            // bf16[256][512] = 65536 floats

constexpr int NB1024 = (N + 1023) / 1024;          // 98 scan blocks
constexpr int NB_GRAM = (N + 127) / 128;           // 782 gram blocks

typedef __attribute__((ext_vector_type(8))) short short8;
typedef __attribute__((ext_vector_type(4))) float floatx4;

__device__ __forceinline__ float4 ld4(const float* p) {
  return *reinterpret_cast<const float4*>(p);
}
__device__ __forceinline__ void st4(float* p, float4 v) {
  *reinterpret_cast<float4*>(p) = v;
}
__device__ __forceinline__ unsigned short f2bf(float f) {
  unsigned u = __float_as_uint(f);
  u += 0x7fff + ((u >> 16) & 1);       // RNE
  return (unsigned short)(u >> 16);
}

// ---------------- K0: pack Wt||Wg -> bf16 Bt[n=256][k=512] ----------------
__global__ __launch_bounds__(256) void k0_cvt(const float* __restrict__ Wt,
    const float* __restrict__ Wg, unsigned short* __restrict__ Bt)
{
  const int idx = blockIdx.x * 256 + threadIdx.x;   // < 131072
  const int k = idx >> 8;       // 0..511
  const int n = idx & 255;      // 0..255
  float v = (n < 128) ? Wt[(size_t)k * H + n] : Wg[(size_t)k * H + (n - 128)];
  Bt[(size_t)n * F + k] = f2bf(v);
}

// ---------------- K1: MFMA fused fc GEMMs, x -> h_t (relu.LN) and h_g (relu.BN) ----------------
// block: 256 thr (4 waves), tile M=64 rows x 256 cols (Wt cols 0-127, Wg cols 128-255)
__global__ __launch_bounds__(256) void k1_mfma(
    const float* __restrict__ x, const unsigned short* __restrict__ Bt,
    const float* __restrict__ bt, const float* __restrict__ lng, const float* __restrict__ lnb,
    const float* __restrict__ bgv, const float* __restrict__ bng, const float* __restrict__ bnb,
    float* __restrict__ ht, float* __restrict__ hg)
{
  __shared__ __align__(16) union {
    struct { unsigned short A[64 * 72]; unsigned short B[256 * 72]; } st;  // 46080 B
    struct { float lns[64 * 132]; float mu[64]; float rs[64]; } ln;        // 34304 B
  } sm;
  const int t = threadIdx.x;
  const int lane = t & 63;
  const int w = t >> 6;
  const int rq = (w >> 1) * 32;     // wave row base: 0 / 32
  const int cq = (w & 1) * 128;     // wave col base: 0 / 128
  const int g = lane >> 4;          // 0..3
  const int m = lane & 15;
  const int M0 = blockIdx.x * 64;

  floatx4 acc[2][8];
#pragma unroll
  for (int rt = 0; rt < 2; ++rt)
#pragma unroll
    for (int ct = 0; ct < 8; ++ct) acc[rt][ct] = (floatx4){0.f, 0.f, 0.f, 0.f};

  const int srow = t >> 2;          // 0..63
  const int scol = (t & 3) * 16;    // 0,16,32,48
  const int grow = (M0 + srow < N) ? (M0 + srow) : (N - 1);
  const float* xp = x + (size_t)grow * F;
  const unsigned short* bsrc = Bt + (size_t)t * F;

  for (int k0 = 0; k0 < F; k0 += 64) {
    // stage A: fp32 -> bf16 -> LDS
#pragma unroll
    for (int j = 0; j < 4; ++j) {
      float4 a4 = ld4(xp + k0 + scol + j * 4);
      ushort4 p;
      p.x = f2bf(a4.x); p.y = f2bf(a4.y); p.z = f2bf(a4.z); p.w = f2bf(a4.w);
      *(ushort4*)(sm.st.A + srow * 72 + scol + j * 4) = p;
    }
    // stage B: n = t, 64 bf16
#pragma unroll
    for (int j = 0; j < 8; ++j)
      *(uint4*)(sm.st.B + t * 72 + j * 8) = *(const uint4*)(bsrc + k0 + j * 8);
    __syncthreads();
#pragma unroll
    for (int kk = 0; kk < 64; kk += 32) {
      short8 af[2], bf[8];
#pragma unroll
      for (int rt = 0; rt < 2; ++rt)
        af[rt] = *(const short8*)(sm.st.A + (rq + rt * 16 + m) * 72 + kk + g * 8);
#pragma unroll
      for (int ct = 0; ct < 8; ++ct)
        bf[ct] = *(const short8*)(sm.st.B + (cq + ct * 16 + m) * 72 + kk + g * 8);
#pragma unroll
      for (int rt = 0; rt < 2; ++rt)
#pragma unroll
        for (int ct = 0; ct < 8; ++ct)
          acc[rt][ct] = __builtin_amdgcn_mfma_f32_16x16x32_bf16(af[rt], bf[ct], acc[rt][ct], 0, 0, 0);
    }
    __syncthreads();
  }
  // epilogue. C/D layout: col = m, row = g*4 + reg (m89-verified)
  if (cq == 0) {
    // trans half: pre-activation + bias into LDS for LN
#pragma unroll
    for (int rt = 0; rt < 2; ++rt)
#pragma unroll
      for (int ct = 0; ct < 8; ++ct) {
        const int col = ct * 16 + m;
        const float b = bt[col];
#pragma unroll
        for (int r = 0; r < 4; ++r)
          sm.ln.lns[(rq + rt * 16 + g * 4 + r) * 132 + col] = acc[rt][ct][r] + b;
      }
  } else {
    // graph half: BN + relu, store hg
#pragma unroll
    for (int rt = 0; rt < 2; ++rt)
#pragma unroll
      for (int ct = 0; ct < 8; ++ct) {
        const int col = ct * 16 + m;
        const float s1 = IBN * bng[col], b0 = bgv[col], b2 = bnb[col];
#pragma unroll
        for (int r = 0; r < 4; ++r) {
          const int row = M0 + rq + rt * 16 + g * 4 + r;
          if (row < N) {
            float v = (acc[rt][ct][r] + b0) * s1 + b2;
            hg[(size_t)row * H + col] = v > 0.f ? v : 0.f;
          }
        }
      }
  }
  __syncthreads();
  if (t < 64) {
    float sum = 0.f, sq = 0.f;
    for (int c2 = 0; c2 < H; ++c2) {
      float v = sm.ln.lns[t * 132 + c2];
      sum += v; sq += v * v;
    }
    float mu = sum * (1.f / H);
    float var = sq * (1.f / H) - mu * mu;
    sm.ln.mu[t] = mu; sm.ln.rs[t] = rsqrtf(var + EPS);
  }
  __syncthreads();
  {
    const int r = t >> 2;
    const int cb = (t & 3) * 32;
    if (M0 + r < N) {
      const float mu = sm.ln.mu[r], rs = sm.ln.rs[r];
#pragma unroll
      for (int j = 0; j < 8; ++j) {
        const int c = cb + j * 4;
        float o[4];
#pragma unroll
        for (int q = 0; q < 4; ++q) {
          float v = (sm.ln.lns[r * 132 + c + q] - mu) * rs * lng[c + q] + lnb[c + q];
          o[q] = v > 0.f ? v : 0.f;
        }
        st4(ht + (size_t)(M0 + r) * H + c, make_float4(o[0], o[1], o[2], o[3]));
      }
    }
  }
}

// ---------------- K2: gram partials (8-way replicated) + fused colsum ----------------
__global__ __launch_bounds__(256) void k2_gram(const float* __restrict__ ht,
                                               float* __restrict__ GP,
                                               float* __restrict__ s)
{
  const int t = threadIdx.x;
  const int base = blockIdx.x * 128;
  const int nend = (base + 128 < N) ? base + 128 : N;
  const int r0 = (t >> 4) * 8;
  const int c0 = (t & 15) * 8;
  float acc[8][8] = {};
  float colacc[8] = {};
  const bool do_col = (t < 16);     // r0 == 0 rows cover all 128 cols via c0
  for (int n = base; n < nend; ++n) {
    const float* hp = ht + (size_t)n * H;
    float4 a0 = ld4(hp + r0), a1 = ld4(hp + r0 + 4);
    float4 b0 = ld4(hp + c0), b1 = ld4(hp + c0 + 4);
    float a[8] = {a0.x, a0.y, a0.z, a0.w, a1.x, a1.y, a1.z, a1.w};
    float b[8] = {b0.x, b0.y, b0.z, b0.w, b1.x, b1.y, b1.z, b1.w};
    if (do_col) {
#pragma unroll
      for (int j = 0; j < 8; ++j) colacc[j] += b[j];
    }
#pragma unroll
    for (int i = 0; i < 8; ++i)
#pragma unroll
      for (int j = 0; j < 8; ++j)
        acc[i][j] += a[i] * b[j];
  }
  float* gp = GP + (size_t)(blockIdx.x & 7) * 16384;
  for (int i = 0; i < 8; ++i)
    for (int j = 0; j < 8; ++j)
      atomicAdd(&gp[(r0 + i) * H + c0 + j], acc[i][j]);
  if (do_col)
    for (int j = 0; j < 8; ++j) atomicAdd(&s[c0 + j], colacc[j]);
}

// ---------------- K2r: reduce 8 gram partials -> G ----------------
__global__ __launch_bounds__(256) void k2r_reduce(const float* __restrict__ GP,
                                                  float* __restrict__ G)
{
  const int i = blockIdx.x * 256 + threadIdx.x;   // < 16384
  float sum = 0.f;
#pragma unroll
  for (int r = 0; r < 8; ++r) sum += GP[(size_t)r * 16384 + i];
  G[i] = sum;
}

// ---------------- K3a: GW = G @ {Wv, Wk, Wq} ----------------
__global__ __launch_bounds__(256) void k3a_gw(const float* __restrict__ G,
    const float* __restrict__ Wv, const float* __restrict__ Wk,
    const float* __restrict__ Wq, float* __restrict__ GW)
{
  const int flat = blockIdx.x * 256 + threadIdx.x;   // < 98304
  const int w = flat >> 15;
  const int rem = flat & 32767;
  const int i = rem >> 8;
  const int j = rem & 255;
  const float* W = (w == 0) ? Wv : (w == 1) ? Wk : Wq;
  float sum = 0.f;
#pragma unroll 8
  for (int k = 0; k < H; ++k) sum += G[i * H + k] * W[k * 256 + j];
  GW[flat] = sum;
}

// ---------------- K3k: ksum/vsum/qsum = s @ W + N*b ----------------
__global__ __launch_bounds__(256) void k3k_sums(const float* __restrict__ s,
    const float* __restrict__ Wk, const float* __restrict__ bk,
    const float* __restrict__ Wv, const float* __restrict__ bv,
    const float* __restrict__ Wq, const float* __restrict__ bq,
    float* __restrict__ ksum, float* __restrict__ vsum, float* __restrict__ qsum)
{
  const int flat = blockIdx.x * 256 + threadIdx.x;   // < 768
  const int w = flat >> 8;
  const int j = flat & 255;
  const float* W = (w == 0) ? Wk : (w == 1) ? Wv : Wq;
  const float* b = (w == 0) ? bk : (w == 1) ? bv : bq;
  float* out = (w == 0) ? ksum : (w == 1) ? vsum : qsum;
  float sum = 0.f;
#pragma unroll 8
  for (int k = 0; k < H; ++k) sum += s[k] * W[k * 256 + j];
  out[j] = sum + NF * b[j];
}

// ---------------- K3b: kv_raw[h,m,d] ----------------
__global__ __launch_bounds__(256) void k3b_kv(const float* __restrict__ GWv,
    const float* __restrict__ s, const float* __restrict__ Wk,
    const float* __restrict__ bk, const float* __restrict__ bv,
    const float* __restrict__ vsum, float* __restrict__ kv)
{
  const int flat = blockIdx.x * 256 + threadIdx.x;   // < 32768
  const int h = flat >> 14;
  const int m = (flat >> 7) & 127;
  const int d = flat & 127;
  float s1 = 0.f, s2 = 0.f;
#pragma unroll 4
  for (int k = 0; k < H; ++k) {
    float wkv = Wk[k * 256 + h * 128 + m];
    s1 += wkv * GWv[k * 256 + h * 128 + d];
    s2 += wkv * s[k];
  }
  kv[flat] = s1 + s2 * bv[h * 128 + d] + bk[h * 128 + m] * vsum[h * 128 + d];
}

// ---------------- K3c: ssq_q, ssq_k, inv ----------------
__global__ __launch_bounds__(256) void k3c_ssq(
    const float* __restrict__ Wk, const float* __restrict__ GWk,
    const float* __restrict__ Wq, const float* __restrict__ GWq,
    const float* __restrict__ bk, const float* __restrict__ ksum,
    const float* __restrict__ bq, const float* __restrict__ qsum,
    float* __restrict__ sc)
{
  __shared__ float red[512];
  const int t = threadIdx.x;
  float pk = 0.f, pq = 0.f;
  for (int i = t; i < 32768; i += 256) {
    pk += Wk[i] * GWk[i];
    pq += Wq[i] * GWq[i];
  }
  pk += 2.f * bk[t] * ksum[t] - NF * bk[t] * bk[t];
  pq += 2.f * bq[t] * qsum[t] - NF * bq[t] * bq[t];
  red[t] = pk; red[256 + t] = pq;
  __syncthreads();
  for (int off = 128; off > 0; off >>= 1) {
    if (t < off) { red[t] += red[t + off]; red[256 + t] += red[256 + t + off]; }
    __syncthreads();
  }
  if (t == 0) {
    float ssq_k = red[0], ssq_q = red[256];
    sc[0] = ssq_q; sc[1] = ssq_k;
    sc[2] = rsqrtf(ssq_q * ssq_k);   // 1/(||q|| * ||k||)
  }
}

// ---------------- K3d: B = Wq @ kv * inv + N*Wv ----------------
__global__ __launch_bounds__(256) void k3d_B(const float* __restrict__ Wq,
    const float* __restrict__ kv, const float* __restrict__ Wv,
    const float* __restrict__ sc, float* __restrict__ B)
{
  const int flat = blockIdx.x * 256 + threadIdx.x;   // < 32768
  const int i = flat >> 8;
  const int j = flat & 255;
  const int h = j >> 7;
  const int d = j & 127;
  const float inv = sc[2];
  float sum = 0.f;
#pragma unroll 4
  for (int m = 0; m < H; ++m)
    sum += Wq[i * 256 + h * 128 + m] * kv[h * 16384 + m * 128 + d];
  B[flat] = sum * inv + NF * Wv[i * 256 + j];
}

// ---------------- K3e: c, u, u0 ----------------
__global__ __launch_bounds__(512) void k3e_small(const float* __restrict__ bq,
    const float* __restrict__ kv, const float* __restrict__ bv,
    const float* __restrict__ Wq, const float* __restrict__ ksum,
    const float* __restrict__ sc, float* __restrict__ cc,
    float* __restrict__ u, float* __restrict__ u0)
{
  const int t = threadIdx.x;
  const float inv = sc[2];
  if (t < 256) {
    const int h = t >> 7, d = t & 127;
    float sum = 0.f;
    for (int m = 0; m < H; ++m) sum += bq[h * 128 + m] * kv[h * 16384 + m * 128 + d];
    cc[t] = sum * inv + NF * bv[t];
  } else {
    const int q = t - 256;
    const int i = q >> 1, h = q & 1;
    float sum = 0.f;
    for (int m = 0; m < H; ++m) sum += Wq[i * 256 + h * 128 + m] * ksum[h * 128 + m];
    u[i * 2 + h] = sum * inv;
  }
  if (t < 2) {
    float sum = 0.f;
    for (int m = 0; m < H; ++m) sum += bq[t * 128 + m] * ksum[t * 128 + m];
    u0[t] = sum * inv + NF;
  }
}

// ---------------- K4: attention apply + residual + LN -> x1 (in-place in ht) ----------------
__global__ __launch_bounds__(256) void k4_attn(float* __restrict__ ht,
    const float* __restrict__ Bc, const float* __restrict__ cc,
    const float* __restrict__ u, const float* __restrict__ u0,
    const float* __restrict__ lng, const float* __restrict__ lnb)
{
  __shared__ float ns[32 * 260];    // +4 pad
  __shared__ float mu_s[32], rs_s[32];
  const int t = threadIdx.x;
  const int R0 = blockIdx.x * 32;
  const int r0 = (t >> 5) * 4;
  const int c0 = (t & 31) * 8;      // 0..248 over 256 (head*128 + d)
  float acc[4][8] = {};
  for (int k0 = 0; k0 < H; k0 += 4) {
    float ax[4][4];
#pragma unroll
    for (int r = 0; r < 4; ++r) {
      float4 a4 = ld4(ht + (size_t)(R0 + r0 + r) * H + k0);
      ax[r][0] = a4.x; ax[r][1] = a4.y; ax[r][2] = a4.z; ax[r][3] = a4.w;
    }
#pragma unroll
    for (int kk = 0; kk < 4; ++kk) {
      float4 b0 = ld4(Bc + (size_t)(k0 + kk) * 256 + c0);
      float4 b1 = ld4(Bc + (size_t)(k0 + kk) * 256 + c0 + 4);
#pragma unroll
      for (int r = 0; r < 4; ++r) {
        float av = ax[r][kk];
        acc[r][0] += av * b0.x; acc[r][1] += av * b0.y;
        acc[r][2] += av * b0.z; acc[r][3] += av * b0.w;
        acc[r][4] += av * b1.x; acc[r][5] += av * b1.y;
        acc[r][6] += av * b1.z; acc[r][7] += av * b1.w;
      }
    }
  }
  const int head = c0 >> 7;
  const float u00 = u0[head];
#pragma unroll
  for (int r = 0; r < 4; ++r) {
    float den = u00;
    const float* hp = ht + (size_t)(R0 + r0 + r) * H;
    for (int k = 0; k < H; k += 4) {
      float4 a4 = ld4(hp + k);
      den += a4.x * u[k * 2 + head] + a4.y * u[(k + 1) * 2 + head]
           + a4.z * u[(k + 2) * 2 + head] + a4.w * u[(k + 3) * 2 + head];
    }
    float rden = 0.5f / den;
#pragma unroll
    for (int j = 0; j < 8; ++j)
      ns[(r0 + r) * 260 + c0 + j] = (acc[r][j] + cc[c0 + j]) * rden;
  }
  __syncthreads();
  const int d0 = (t & 15) * 8;
  const int rr0 = (t >> 4) * 2;
#pragma unroll
  for (int rr = 0; rr < 2; ++rr) {
    const int r = rr0 + rr;
#pragma unroll
    for (int j = 0; j < 8; ++j) {
      const int d = d0 + j;
      float attn = ns[r * 260 + d] + ns[r * 260 + 128 + d];  // mean/2 already folded
      float hm = (attn + ht[(size_t)(R0 + r) * H + d]) * 0.5f;
      ns[r * 260 + d] = hm;          // owner-exclusive slot: safe in-place
    }
  }
  __syncthreads();
  if (t < 32) {
    float sum = 0.f, sq = 0.f;
    for (int c2 = 0; c2 < H; ++c2) {
      float v = ns[t * 260 + c2];
      sum += v; sq += v * v;
    }
    float mu = sum * (1.f / H);
    float var = sq * (1.f / H) - mu * mu;
    mu_s[t] = mu; rs_s[t] = rsqrtf(var + EPS);
  }
  __syncthreads();
#pragma unroll
  for (int rr = 0; rr < 2; ++rr) {
    const int r = rr0 + rr;
    float mu = mu_s[r], rs = rs_s[r];
    float o[8];
#pragma unroll
    for (int j = 0; j < 8; ++j) {
      const int d = d0 + j;
      float v = (ns[r * 260 + d] - mu) * rs * lng[d] + lnb[d];
      o[j] = v > 0.f ? v : 0.f;
    }
    st4(ht + (size_t)(R0 + r) * H + d0, make_float4(o[0], o[1], o[2], o[3]));
    st4(ht + (size_t)(R0 + r) * H + d0 + 4, make_float4(o[4], o[5], o[6], o[7]));
  }
}

// ---------------- K5: in-degree (int counts) ----------------
__global__ __launch_bounds__(256) void k5_deg(const int* __restrict__ ei,
                                              int* __restrict__ cnt)
{
  const int i = blockIdx.x * 256 + threadIdx.x;
  if (i < E) atomicAdd(&cnt[ei[E + i]], 1);
}

// ---------------- scan1: per-1024-chunk sums ----------------
__global__ __launch_bounds__(256) void k_scan1(const int* __restrict__ cnt,
                                               int* __restrict__ bsum)
{
  __shared__ int red[256];
  const int t = threadIdx.x;
  const int base = blockIdx.x * 1024 + t * 4;
  int s = 0;
#pragma unroll
  for (int j = 0; j < 4; ++j) {
    int idx = base + j;
    if (idx < N) s += cnt[idx];
  }
  red[t] = s;
  __syncthreads();
  for (int off = 128; off > 0; off >>= 1) {
    if (t < off) red[t] += red[t + off];
    __syncthreads();
  }
  if (t == 0) bsum[blockIdx.x] = red[0];
}

// ---------------- scan2: serial exclusive scan of 98 block sums ----------------
__global__ void k_scan2(int* __restrict__ bsum)
{
  if (threadIdx.x == 0 && blockIdx.x == 0) {
    int run = 0;
    for (int b = 0; b < NB1024; ++b) {
      int v = bsum[b];
      bsum[b] = run;
      run += v;
    }
  }
}

// ---------------- scan3: intra-chunk exclusive scan -> ptr, cur ----------------
__global__ __launch_bounds__(256) void k_scan3(const int* __restrict__ cnt,
    const int* __restrict__ bsum, int* __restrict__ ptr, int* __restrict__ cur)
{
  __shared__ int part[256];
  const int t = threadIdx.x;
  const int base = blockIdx.x * 1024 + t * 4;
  int v[4];
  int tsum = 0;
#pragma unroll
  for (int j = 0; j < 4; ++j) {
    int idx = base + j;
    v[j] = (idx < N) ? cnt[idx] : 0;
    tsum += v[j];
  }
  part[t] = tsum;
  __syncthreads();
  for (int off = 1; off < 256; off <<= 1) {
    int add = (t >= off) ? part[t - off] : 0;
    __syncthreads();
    part[t] += add;
    __syncthreads();
  }
  int run = bsum[blockIdx.x] + part[t] - tsum;
#pragma unroll
  for (int j = 0; j < 4; ++j) {
    int idx = base + j;
    if (idx < N) { ptr[idx] = run; cur[idx] = run; }
    run += v[j];
  }
}

// ---------------- K6a: place edges into destination buckets ----------------
__global__ __launch_bounds__(256) void k6a_place(const int* __restrict__ ei,
    const int* __restrict__ cnt, int* __restrict__ cur,
    int* __restrict__ srow, float* __restrict__ sval)
{
  const int e = blockIdx.x * 256 + threadIdx.x;
  if (e >= E) return;
  const int r = ei[e];
  const int c = ei[E + e];
  const int p = atomicAdd(&cur[c], 1);
  srow[p] = r;
  const int dr = cnt[r];
  const float dv = (float)dr * (float)cnt[c];
  sval[p] = (dr > 0) ? rsqrtf(dv) : 0.f;   // nan_to_num(inf)=0 when deg[row]==0
}

// ---------------- K6b: gather-accumulate agg[n] = sum val*hg[row] ----------------
__global__ __launch_bounds__(256) void k6b_gather(const int* __restrict__ ptr,
    const int* __restrict__ cnt, const int* __restrict__ srow,
    const float* __restrict__ sval, const float* __restrict__ hg,
    float* __restrict__ agg)
{
  const int t = threadIdx.x;
  const int n = blockIdx.x * 8 + (t >> 5);     // 8 nodes per block
  const int lane4 = (t & 31) * 4;
  const int start = ptr[n];
  const int end = start + cnt[n];
  float4 acc = make_float4(0.f, 0.f, 0.f, 0.f);
  int e = start;
  for (; e + 1 < end; e += 2) {
    int r0 = srow[e], r1 = srow[e + 1];
    float v0 = sval[e], v1 = sval[e + 1];
    float4 h0 = ld4(hg + (size_t)r0 * H + lane4);
    float4 h1 = ld4(hg + (size_t)r1 * H + lane4);
    acc.x += v0 * h0.x + v1 * h1.x;
    acc.y += v0 * h0.y + v1 * h1.y;
    acc.z += v0 * h0.z + v1 * h1.z;
    acc.w += v0 * h0.w + v1 * h1.w;
  }
  if (e < end) {
    int r0 = srow[e];
    float v0 = sval[e];
    float4 h0 = ld4(hg + (size_t)r0 * H + lane4);
    acc.x += v0 * h0.x;
    acc.y += v0 * h0.y;
    acc.z += v0 * h0.z;
    acc.w += v0 * h0.w;
  }
  st4(agg + (size_t)n * H + lane4, acc);
}

// ---------------- K7: conv GEMM + BN + relu + residual -> x2 (in-place in hg) ----------------
__global__ __launch_bounds__(256) void k7_conv(const float* __restrict__ agg,
    float* __restrict__ hg, const float* __restrict__ Wc,
    const float* __restrict__ cb, const float* __restrict__ g1,
    const float* __restrict__ b1)
{
  const int t = threadIdx.x;
  const int R0 = blockIdx.x * 32;
  const int r0 = (t >> 5) * 4;
  const int c0 = (t & 31) * 4;
  float acc[4][4] = {};
  for (int k0 = 0; k0 < H; k0 += 4) {
    float ax[4][4];
#pragma unroll
    for (int r = 0; r < 4; ++r) {
      float4 a4 = ld4(agg + (size_t)(R0 + r0 + r) * H + k0);
      ax[r][0] = a4.x; ax[r][1] = a4.y; ax[r][2] = a4.z; ax[r][3] = a4.w;
    }
#pragma unroll
    for (int kk = 0; kk < 4; ++kk) {
      float4 w = ld4(Wc + (size_t)(k0 + kk) * H + c0);
#pragma unroll
      for (int r = 0; r < 4; ++r) {
        float av = ax[r][kk];
        acc[r][0] += av * w.x; acc[r][1] += av * w.y;
        acc[r][2] += av * w.z; acc[r][3] += av * w.w;
      }
    }
  }
#pragma unroll
  for (int r = 0; r < 4; ++r) {
    size_t off = (size_t)(R0 + r0 + r) * H + c0;
    float4 res = ld4(hg + off);
    float rsv[4] = {res.x, res.y, res.z, res.w};
    float o[4];
#pragma unroll
    for (int j = 0; j < 4; ++j) {
      float v = (acc[r][j] + cb[c0 + j]) * IBN * g1[c0 + j] + b1[c0 + j];
      v = v > 0.f ? v : 0.f;
      o[j] = v + rsv[j];
    }
    st4(hg + off, make_float4(o[0], o[1], o[2], o[3]));
  }
}

// ---------------- K8: out = (0.8*x2 + 0.2*x1) @ fc_w + fc_b ----------------
__global__ __launch_bounds__(256) void k8_out(const float* __restrict__ ht,
    const float* __restrict__ hg, const float* __restrict__ W,
    const float* __restrict__ bias, float* __restrict__ out)
{
  const int t = threadIdx.x;
  const int R0 = blockIdx.x * 32;
  const int rr0 = (t >> 4) * 2;
  const int c0 = (t & 15) * 4;
  float acc[2][4] = {};
  for (int k0 = 0; k0 < H; k0 += 4) {
    float ax[2][4];
#pragma unroll
    for (int r = 0; r < 2; ++r) {
      size_t off = (size_t)(R0 + rr0 + r) * H + k0;
      float4 a1 = ld4(ht + off);
      float4 a2 = ld4(hg + off);
      ax[r][0] = 0.2f * a1.x + 0.8f * a2.x;
      ax[r][1] = 0.2f * a1.y + 0.8f * a2.y;
      ax[r][2] = 0.2f * a1.z + 0.8f * a2.z;
      ax[r][3] = 0.2f * a1.w + 0.8f * a2.w;
    }
#pragma unroll
    for (int kk = 0; kk < 4; ++kk) {
      float4 w = ld4(W + (size_t)(k0 + kk) * C + c0);
#pragma unroll
      for (int r = 0; r < 2; ++r) {
        float av = ax[r][kk];
        acc[r][0] += av * w.x; acc[r][1] += av * w.y;
        acc[r][2] += av * w.z; acc[r][3] += av * w.w;
      }
    }
  }
#pragma unroll
  for (int r = 0; r < 2; ++r) {
    float o[4];
#pragma unroll
    for (int j = 0; j < 4; ++j) o[j] = acc[r][j] + bias[c0 + j];
    st4(out + (size_t)(R0 + rr0 + r) * C + c0, make_float4(o[0], o[1], o[2], o[3]));
  }
}

// ---------------- launch ----------------
extern "C" void kernel_launch(void* const* d_in, const int* in_sizes, int n_in,
                              void* d_out, int out_size, void* d_ws, size_t ws_size,
                              hipStream_t stream) {
  (void)in_sizes; (void)n_in; (void)out_size; (void)ws_size;
  const float* x       = (const float*)d_in[0];
  const int*   ei      = (const int*)d_in[1];
  const float* t_fc_w  = (const float*)d_in[2];
  const float* t_fc_b  = (const float*)d_in[3];
  const float* t_ln0_g = (const float*)d_in[4];
  const float* t_ln0_b = (const float*)d_in[5];
  const float* t_wq_w  = (const float*)d_in[6];
  const float* t_wq_b  = (const float*)d_in[7];
  const float* t_wk_w  = (const float*)d_in[8];
  const float* t_wk_b  = (const float*)d_in[9];
  const float* t_wv_w  = (const float*)d_in[10];
  const float* t_wv_b  = (const float*)d_in[11];
  const float* t_ln1_g = (const float*)d_in[12];
  const float* t_ln1_b = (const float*)d_in[13];
  const float* g_fc_w  = (const float*)d_in[14];
  const float* g_fc_b  = (const float*)d_in[15];
  const float* g_bn0_g = (const float*)d_in[16];
  const float* g_bn0_b = (const float*)d_in[17];
  const float* g_cv_w  = (const float*)d_in[18];
  const float* g_cv_b  = (const float*)d_in[19];
  const float* g_bn1_g = (const float*)d_in[20];
  const float* g_bn1_b = (const float*)d_in[21];
  const float* fc_w    = (const float*)d_in[22];
  const float* fc_b    = (const float*)d_in[23];

  float* W    = (float*)d_ws;
  float* ht   = W + OFF_HT;
  float* hg   = W + OFF_HG;
  float* agg  = W + OFF_AGG;
  int*   cnt  = (int*)(W + OFF_CNT);
  float* GP   = W + OFF_GP;
  float* G    = W + OFF_G;
  float* s    = W + OFF_S;
  int*   ptr  = (int*)(W + OFF_PTR);
  int*   cur  = (int*)(W + OFF_CUR);
  int*   bsum = (int*)(W + OFF_BS);
  int*   srow = (int*)(W + OFF_SROW);
  float* sval = W + OFF_SVAL;
  float* gw   = W + OFF_GWV;
  float* kv   = W + OFF_KV;
  float* ksum = W + OFF_KSUM;
  float* vsum = W + OFF_VSUM;
  float* qsum = W + OFF_QSUM;
  float* sc   = W + OFF_SC;
  float* Bc   = W + OFF_B;
  float* cc   = W + OFF_CC;
  float* u    = W + OFF_U;
  float* u0   = W + OFF_U0;
  unsigned short* Bt = (unsigned short*)(W + OFF_BT);

  hipMemsetAsync(W + ZERO_BEGIN, 0, ZERO_COUNT * sizeof(float), stream);

  // weight pack for MFMA k1
  k0_cvt<<<512, 256, 0, stream>>>(t_fc_w, g_fc_w, Bt);

  // graph branch CSR build (independent of k1)
  k5_deg<<<(E + 255) / 256, 256, 0, stream>>>(ei, cnt);
  k_scan1<<<NB1024, 256, 0, stream>>>(cnt, bsum);
  k_scan2<<<1, 64, 0, stream>>>(bsum);
  k_scan3<<<NB1024, 256, 0, stream>>>(cnt, bsum, ptr, cur);
  k6a_place<<<E / 256, 256, 0, stream>>>(ei, cnt, cur, srow, sval);

  k1_mfma<<<(N + 63) / 64, 256, 0, stream>>>(x, Bt, t_fc_b, t_ln0_g, t_ln0_b,
                                             g_fc_b, g_bn0_g, g_bn0_b, ht, hg);
  // graph aggregation (gather)
  k6b_gather<<<N / 8, 256, 0, stream>>>(ptr, cnt, srow, sval, hg, agg);
  // trans branch reductions (gram + fused colsum, 8-way partials)
  k2_gram<<<NB_GRAM, 256, 0, stream>>>(ht, GP, s);
  k2r_reduce<<<64, 256, 0, stream>>>(GP, G);
  k3a_gw<<<384, 256, 0, stream>>>(G, t_wv_w, t_wk_w, t_wq_w, gw);
  k3k_sums<<<3, 256, 0, stream>>>(s, t_wk_w, t_wk_b, t_wv_w, t_wv_b, t_wq_w, t_wq_b,
                                  ksum, vsum, qsum);
  k3b_kv<<<128, 256, 0, stream>>>(gw, s, t_wk_w, t_wk_b, t_wv_b, vsum, kv);
  k3c_ssq<<<1, 256, 0, stream>>>(t_wk_w, gw + 32768, t_wq_w, gw + 65536,
                                 t_wk_b, ksum, t_wq_b, qsum, sc);
  k3d_B<<<128, 256, 0, stream>>>(t_wq_w, kv, t_wv_w, sc, Bc);
  k3e_small<<<1, 512, 0, stream>>>(t_wq_b, kv, t_wv_b, t_wq_w, ksum, sc, cc, u, u0);
  k4_attn<<<N / 32, 256, 0, stream>>>(ht, Bc, cc, u, u0, t_ln1_g, t_ln1_b);
  // graph tail + output
  k7_conv<<<N / 32, 256, 0, stream>>>(agg, hg, g_cv_w, g_cv_b, g_bn1_g, g_bn1_b);
  k8_out<<<N / 32, 256, 0, stream>>>(ht, hg, fc_w, fc_b, (float*)d_out);
}

// Round 5
// 1340.615 us; speedup vs baseline: 1.3186x; 1.3186x over previous
//
#include <hip/hip_runtime.h>

// ---------------- problem constants ----------------
constexpr int N = 100000;
constexpr int F = 512;
constexpr int H = 128;
constexpr int E = 1600000;
constexpr int C = 64;
constexpr float EPS = 1e-5f;
constexpr float NF = 100000.0f;     // number of nodes as float
constexpr float IBN = 0.999995000037f; // 1/sqrt(1+1e-5)

// ---------------- workspace layout (float offsets) ----------------
constexpr size_t OFF_HT   = 0;                     // [N,H] trans hidden, later x1 (in-place)
constexpr size_t OFF_HG   = 12800000;              // [N,H] graph hidden, later x2 (in-place)
constexpr size_t OFF_AGG  = 25600000;              // [N,H]; FIRST reused as gram partials, THEN gather output
constexpr size_t OFF_CNT  = 38400000;              // int[N] in-degree  (zeroed)
constexpr size_t OFF_S    = 38500000;              // [128] colsum (written by k2r)
constexpr size_t OFF_G    = 38500128;              // [128,128] gram (written by k2r)
constexpr size_t OFF_PTR  = 38516512;              // int[N] CSR bucket starts
constexpr size_t OFF_CUR  = 38616512;              // int[N] placement cursors
constexpr size_t OFF_BS   = 38716512;              // int[128] scan block offsets
constexpr size_t OFF_SROW = 38716640;              // int[E] sorted src rows
constexpr size_t OFF_SVAL = 40316640;              // float[E] sorted edge weights
constexpr size_t OFF_GWV  = 41916640;              // 3 x [128,256]: G@Wv, G@Wk, G@Wq
constexpr size_t OFF_KV   = OFF_GWV + 3 * 32768;   // [2,128,128] kv_raw
constexpr size_t OFF_KSUM = OFF_KV + 32768;        // [256]
constexpr size_t OFF_VSUM = OFF_KSUM + 256;        // [256]
constexpr size_t OFF_QSUM = OFF_VSUM + 256;        // [256]
constexpr size_t OFF_SC   = OFF_QSUM + 256;        // [4]
constexpr size_t OFF_B    = OFF_SC + 4;            // [128,256]
constexpr size_t OFF_CC   = OFF_B + 32768;         // [256]
constexpr size_t OFF_U    = OFF_CC + 256;          // [128,2]
constexpr size_t OFF_U0   = OFF_U + 256;           // [2] (+2 pad)
constexpr size_t OFF_BT   = OFF_U0 + 4;            // bf16[256][512] = 65536 floats

constexpr int NB1024 = (N + 1023) / 1024;          // 98 scan blocks
constexpr int NB_GRAM = (N + 255) / 256;           // 391 gram blocks
constexpr size_t SP_BASE = (size_t)NB_GRAM * 16384; // colsum partials offset inside agg

typedef __attribute__((ext_vector_type(8))) short short8;
typedef __attribute__((ext_vector_type(4))) float floatx4;

__device__ __forceinline__ float4 ld4(const float* p) {
  return *reinterpret_cast<const float4*>(p);
}
__device__ __forceinline__ void st4(float* p, float4 v) {
  *reinterpret_cast<float4*>(p) = v;
}
__device__ __forceinline__ unsigned short f2bf(float f) {
  unsigned u = __float_as_uint(f);
  u += 0x7fff + ((u >> 16) & 1);       // RNE
  return (unsigned short)(u >> 16);
}

// ---------------- K0: pack Wt||Wg -> bf16 Bt[n=256][k=512] ----------------
__global__ __launch_bounds__(256) void k0_cvt(const float* __restrict__ Wt,
    const float* __restrict__ Wg, unsigned short* __restrict__ Bt)
{
  const int idx = blockIdx.x * 256 + threadIdx.x;   // < 131072
  const int k = idx >> 8;       // 0..511
  const int n = idx & 255;      // 0..255
  float v = (n < 128) ? Wt[(size_t)k * H + n] : Wg[(size_t)k * H + (n - 128)];
  Bt[(size_t)n * F + k] = f2bf(v);
}

// ---------------- K1: MFMA fused fc GEMMs, x -> h_t (relu.LN) and h_g (relu.BN) ----------------
// block: 256 thr (4 waves), tile M=64 rows x 256 cols (Wt cols 0-127, Wg cols 128-255)
__global__ __launch_bounds__(256) void k1_mfma(
    const float* __restrict__ x, const unsigned short* __restrict__ Bt,
    const float* __restrict__ bt, const float* __restrict__ lng, const float* __restrict__ lnb,
    const float* __restrict__ bgv, const float* __restrict__ bng, const float* __restrict__ bnb,
    float* __restrict__ ht, float* __restrict__ hg)
{
  __shared__ __align__(16) union {
    struct { unsigned short A[64 * 72]; unsigned short B[256 * 72]; } st;  // 46080 B
    struct { float lns[64 * 132]; float mu[64]; float rs[64]; } ln;        // 34304 B
  } sm;
  const int t = threadIdx.x;
  const int lane = t & 63;
  const int w = t >> 6;
  const int rq = (w >> 1) * 32;     // wave row base: 0 / 32
  const int cq = (w & 1) * 128;     // wave col base: 0 / 128
  const int g = lane >> 4;          // 0..3
  const int m = lane & 15;
  const int M0 = blockIdx.x * 64;

  floatx4 acc[2][8];
#pragma unroll
  for (int rt = 0; rt < 2; ++rt)
#pragma unroll
    for (int ct = 0; ct < 8; ++ct) acc[rt][ct] = (floatx4){0.f, 0.f, 0.f, 0.f};

  const int srow = t >> 2;          // 0..63
  const int scol = (t & 3) * 16;    // 0,16,32,48
  const int grow = (M0 + srow < N) ? (M0 + srow) : (N - 1);
  const float* xp = x + (size_t)grow * F;
  const unsigned short* bsrc = Bt + (size_t)t * F;

  for (int k0 = 0; k0 < F; k0 += 64) {
    // stage A: fp32 -> bf16 -> LDS
#pragma unroll
    for (int j = 0; j < 4; ++j) {
      float4 a4 = ld4(xp + k0 + scol + j * 4);
      ushort4 p;
      p.x = f2bf(a4.x); p.y = f2bf(a4.y); p.z = f2bf(a4.z); p.w = f2bf(a4.w);
      *(ushort4*)(sm.st.A + srow * 72 + scol + j * 4) = p;
    }
    // stage B: n = t, 64 bf16
#pragma unroll
    for (int j = 0; j < 8; ++j)
      *(uint4*)(sm.st.B + t * 72 + j * 8) = *(const uint4*)(bsrc + k0 + j * 8);
    __syncthreads();
#pragma unroll
    for (int kk = 0; kk < 64; kk += 32) {
      short8 af[2], bf[8];
#pragma unroll
      for (int rt = 0; rt < 2; ++rt)
        af[rt] = *(const short8*)(sm.st.A + (rq + rt * 16 + m) * 72 + kk + g * 8);
#pragma unroll
      for (int ct = 0; ct < 8; ++ct)
        bf[ct] = *(const short8*)(sm.st.B + (cq + ct * 16 + m) * 72 + kk + g * 8);
#pragma unroll
      for (int rt = 0; rt < 2; ++rt)
#pragma unroll
        for (int ct = 0; ct < 8; ++ct)
          acc[rt][ct] = __builtin_amdgcn_mfma_f32_16x16x32_bf16(af[rt], bf[ct], acc[rt][ct], 0, 0, 0);
    }
    __syncthreads();
  }
  // epilogue. C/D layout: col = m, row = g*4 + reg (m89-verified)
  if (cq == 0) {
    // trans half: pre-activation + bias into LDS for LN
#pragma unroll
    for (int rt = 0; rt < 2; ++rt)
#pragma unroll
      for (int ct = 0; ct < 8; ++ct) {
        const int col = ct * 16 + m;
        const float b = bt[col];
#pragma unroll
        for (int r = 0; r < 4; ++r)
          sm.ln.lns[(rq + rt * 16 + g * 4 + r) * 132 + col] = acc[rt][ct][r] + b;
      }
  } else {
    // graph half: BN + relu, store hg
#pragma unroll
    for (int rt = 0; rt < 2; ++rt)
#pragma unroll
      for (int ct = 0; ct < 8; ++ct) {
        const int col = ct * 16 + m;
        const float s1 = IBN * bng[col], b0 = bgv[col], b2 = bnb[col];
#pragma unroll
        for (int r = 0; r < 4; ++r) {
          const int row = M0 + rq + rt * 16 + g * 4 + r;
          if (row < N) {
            float v = (acc[rt][ct][r] + b0) * s1 + b2;
            hg[(size_t)row * H + col] = v > 0.f ? v : 0.f;
          }
        }
      }
  }
  __syncthreads();
  if (t < 64) {
    float sum = 0.f, sq = 0.f;
    for (int c2 = 0; c2 < H; ++c2) {
      float v = sm.ln.lns[t * 132 + c2];
      sum += v; sq += v * v;
    }
    float mu = sum * (1.f / H);
    float var = sq * (1.f / H) - mu * mu;
    sm.ln.mu[t] = mu; sm.ln.rs[t] = rsqrtf(var + EPS);
  }
  __syncthreads();
  {
    const int r = t >> 2;
    const int cb = (t & 3) * 32;
    if (M0 + r < N) {
      const float mu = sm.ln.mu[r], rs = sm.ln.rs[r];
#pragma unroll
      for (int j = 0; j < 8; ++j) {
        const int c = cb + j * 4;
        float o[4];
#pragma unroll
        for (int q = 0; q < 4; ++q) {
          float v = (sm.ln.lns[r * 132 + c + q] - mu) * rs * lng[c + q] + lnb[c + q];
          o[q] = v > 0.f ? v : 0.f;
        }
        st4(ht + (size_t)(M0 + r) * H + c, make_float4(o[0], o[1], o[2], o[3]));
      }
    }
  }
}

// ---------------- K2: gram + colsum partials, NO atomics ----------------
// block b: rows [b*256, b*256+256); writes private 128x128 partial + 128 colsum partial
__global__ __launch_bounds__(256) void k2_gram(const float* __restrict__ ht,
                                               float* __restrict__ gp,   // [NB_GRAM][16384]
                                               float* __restrict__ sp)   // [NB_GRAM][128]
{
  const int t = threadIdx.x;
  const int b = blockIdx.x;
  const int base = b * 256;
  const int nend = (base + 256 < N) ? base + 256 : N;
  const int r0 = (t >> 4) * 8;
  const int c0 = (t & 15) * 8;
  float acc[8][8] = {};
  float colacc[8] = {};
  const bool do_col = (t < 16);     // t<16 covers all 128 cols via c0
  int n = base;
  for (; n + 1 < nend; n += 2) {
    const float* hp0 = ht + (size_t)n * H;
    const float* hp1 = hp0 + H;
    float4 a00 = ld4(hp0 + r0), a01 = ld4(hp0 + r0 + 4);
    float4 b00 = ld4(hp0 + c0), b01 = ld4(hp0 + c0 + 4);
    float4 a10 = ld4(hp1 + r0), a11 = ld4(hp1 + r0 + 4);
    float4 b10 = ld4(hp1 + c0), b11 = ld4(hp1 + c0 + 4);
    float a0[8] = {a00.x, a00.y, a00.z, a00.w, a01.x, a01.y, a01.z, a01.w};
    float b0[8] = {b00.x, b00.y, b00.z, b00.w, b01.x, b01.y, b01.z, b01.w};
    float a1[8] = {a10.x, a10.y, a10.z, a10.w, a11.x, a11.y, a11.z, a11.w};
    float b1[8] = {b10.x, b10.y, b10.z, b10.w, b11.x, b11.y, b11.z, b11.w};
    if (do_col) {
#pragma unroll
      for (int j = 0; j < 8; ++j) colacc[j] += b0[j] + b1[j];
    }
#pragma unroll
    for (int i = 0; i < 8; ++i)
#pragma unroll
      for (int j = 0; j < 8; ++j)
        acc[i][j] += a0[i] * b0[j] + a1[i] * b1[j];
  }
  if (n < nend) {
    const float* hp0 = ht + (size_t)n * H;
    float4 a00 = ld4(hp0 + r0), a01 = ld4(hp0 + r0 + 4);
    float4 b00 = ld4(hp0 + c0), b01 = ld4(hp0 + c0 + 4);
    float a0[8] = {a00.x, a00.y, a00.z, a00.w, a01.x, a01.y, a01.z, a01.w};
    float b0[8] = {b00.x, b00.y, b00.z, b00.w, b01.x, b01.y, b01.z, b01.w};
    if (do_col) {
#pragma unroll
      for (int j = 0; j < 8; ++j) colacc[j] += b0[j];
    }
#pragma unroll
    for (int i = 0; i < 8; ++i)
#pragma unroll
      for (int j = 0; j < 8; ++j)
        acc[i][j] += a0[i] * b0[j];
  }
  float* g = gp + (size_t)b * 16384;
#pragma unroll
  for (int i = 0; i < 8; ++i) {
    st4(&g[(r0 + i) * H + c0], make_float4(acc[i][0], acc[i][1], acc[i][2], acc[i][3]));
    st4(&g[(r0 + i) * H + c0 + 4], make_float4(acc[i][4], acc[i][5], acc[i][6], acc[i][7]));
  }
  if (do_col) {
    float* spb = sp + (size_t)b * 128;
    st4(&spb[c0], make_float4(colacc[0], colacc[1], colacc[2], colacc[3]));
    st4(&spb[c0 + 4], make_float4(colacc[4], colacc[5], colacc[6], colacc[7]));
  }
}

// ---------------- K2r: reduce partials -> G, s ----------------
__global__ __launch_bounds__(256) void k2r_reduce(const float* __restrict__ gp,
    const float* __restrict__ sp, float* __restrict__ G, float* __restrict__ s)
{
  const int i = blockIdx.x * 256 + threadIdx.x;   // < 16384
  float s0 = 0.f, s1 = 0.f, s2 = 0.f, s3 = 0.f;
  int b = 0;
  for (; b + 3 < NB_GRAM; b += 4) {
    s0 += gp[(size_t)b * 16384 + i];
    s1 += gp[(size_t)(b + 1) * 16384 + i];
    s2 += gp[(size_t)(b + 2) * 16384 + i];
    s3 += gp[(size_t)(b + 3) * 16384 + i];
  }
  for (; b < NB_GRAM; ++b) s0 += gp[(size_t)b * 16384 + i];
  G[i] = (s0 + s1) + (s2 + s3);
  if (blockIdx.x == 0 && threadIdx.x < 128) {
    float t0 = 0.f, t1 = 0.f;
    int bb = 0;
    for (; bb + 1 < NB_GRAM; bb += 2) {
      t0 += sp[(size_t)bb * 128 + threadIdx.x];
      t1 += sp[(size_t)(bb + 1) * 128 + threadIdx.x];
    }
    for (; bb < NB_GRAM; ++bb) t0 += sp[(size_t)bb * 128 + threadIdx.x];
    s[threadIdx.x] = t0 + t1;
  }
}

// ---------------- K3a: GW = G @ {Wv, Wk, Wq} ----------------
__global__ __launch_bounds__(256) void k3a_gw(const float* __restrict__ G,
    const float* __restrict__ Wv, const float* __restrict__ Wk,
    const float* __restrict__ Wq, float* __restrict__ GW)
{
  const int flat = blockIdx.x * 256 + threadIdx.x;   // < 98304
  const int w = flat >> 15;
  const int rem = flat & 32767;
  const int i = rem >> 8;
  const int j = rem & 255;
  const float* W = (w == 0) ? Wv : (w == 1) ? Wk : Wq;
  float sum = 0.f;
#pragma unroll 8
  for (int k = 0; k < H; ++k) sum += G[i * H + k] * W[k * 256 + j];
  GW[flat] = sum;
}

// ---------------- K3k: ksum/vsum/qsum = s @ W + N*b ----------------
__global__ __launch_bounds__(256) void k3k_sums(const float* __restrict__ s,
    const float* __restrict__ Wk, const float* __restrict__ bk,
    const float* __restrict__ Wv, const float* __restrict__ bv,
    const float* __restrict__ Wq, const float* __restrict__ bq,
    float* __restrict__ ksum, float* __restrict__ vsum, float* __restrict__ qsum)
{
  const int flat = blockIdx.x * 256 + threadIdx.x;   // < 768
  const int w = flat >> 8;
  const int j = flat & 255;
  const float* W = (w == 0) ? Wk : (w == 1) ? Wv : Wq;
  const float* b = (w == 0) ? bk : (w == 1) ? bv : bq;
  float* out = (w == 0) ? ksum : (w == 1) ? vsum : qsum;
  float sum = 0.f;
#pragma unroll 8
  for (int k = 0; k < H; ++k) sum += s[k] * W[k * 256 + j];
  out[j] = sum + NF * b[j];
}

// ---------------- K3b: kv_raw[h,m,d] ----------------
__global__ __launch_bounds__(256) void k3b_kv(const float* __restrict__ GWv,
    const float* __restrict__ s, const float* __restrict__ Wk,
    const float* __restrict__ bk, const float* __restrict__ bv,
    const float* __restrict__ vsum, float* __restrict__ kv)
{
  const int flat = blockIdx.x * 256 + threadIdx.x;   // < 32768
  const int h = flat >> 14;
  const int m = (flat >> 7) & 127;
  const int d = flat & 127;
  float s1 = 0.f, s2 = 0.f;
#pragma unroll 4
  for (int k = 0; k < H; ++k) {
    float wkv = Wk[k * 256 + h * 128 + m];
    s1 += wkv * GWv[k * 256 + h * 128 + d];
    s2 += wkv * s[k];
  }
  kv[flat] = s1 + s2 * bv[h * 128 + d] + bk[h * 128 + m] * vsum[h * 128 + d];
}

// ---------------- K3c: ssq_q, ssq_k, inv ----------------
__global__ __launch_bounds__(256) void k3c_ssq(
    const float* __restrict__ Wk, const float* __restrict__ GWk,
    const float* __restrict__ Wq, const float* __restrict__ GWq,
    const float* __restrict__ bk, const float* __restrict__ ksum,
    const float* __restrict__ bq, const float* __restrict__ qsum,
    float* __restrict__ sc)
{
  __shared__ float red[512];
  const int t = threadIdx.x;
  float pk = 0.f, pq = 0.f;
  for (int i = t; i < 32768; i += 256) {
    pk += Wk[i] * GWk[i];
    pq += Wq[i] * GWq[i];
  }
  pk += 2.f * bk[t] * ksum[t] - NF * bk[t] * bk[t];
  pq += 2.f * bq[t] * qsum[t] - NF * bq[t] * bq[t];
  red[t] = pk; red[256 + t] = pq;
  __syncthreads();
  for (int off = 128; off > 0; off >>= 1) {
    if (t < off) { red[t] += red[t + off]; red[256 + t] += red[256 + t + off]; }
    __syncthreads();
  }
  if (t == 0) {
    float ssq_k = red[0], ssq_q = red[256];
    sc[0] = ssq_q; sc[1] = ssq_k;
    sc[2] = rsqrtf(ssq_q * ssq_k);   // 1/(||q|| * ||k||)
  }
}

// ---------------- K3d: B = Wq @ kv * inv + N*Wv ----------------
__global__ __launch_bounds__(256) void k3d_B(const float* __restrict__ Wq,
    const float* __restrict__ kv, const float* __restrict__ Wv,
    const float* __restrict__ sc, float* __restrict__ B)
{
  const int flat = blockIdx.x * 256 + threadIdx.x;   // < 32768
  const int i = flat >> 8;
  const int j = flat & 255;
  const int h = j >> 7;
  const int d = j & 127;
  const float inv = sc[2];
  float sum = 0.f;
#pragma unroll 4
  for (int m = 0; m < H; ++m)
    sum += Wq[i * 256 + h * 128 + m] * kv[h * 16384 + m * 128 + d];
  B[flat] = sum * inv + NF * Wv[i * 256 + j];
}

// ---------------- K3e: c, u, u0 ----------------
__global__ __launch_bounds__(512) void k3e_small(const float* __restrict__ bq,
    const float* __restrict__ kv, const float* __restrict__ bv,
    const float* __restrict__ Wq, const float* __restrict__ ksum,
    const float* __restrict__ sc, float* __restrict__ cc,
    float* __restrict__ u, float* __restrict__ u0)
{
  const int t = threadIdx.x;
  const float inv = sc[2];
  if (t < 256) {
    const int h = t >> 7, d = t & 127;
    float sum = 0.f;
    for (int m = 0; m < H; ++m) sum += bq[h * 128 + m] * kv[h * 16384 + m * 128 + d];
    cc[t] = sum * inv + NF * bv[t];
  } else {
    const int q = t - 256;
    const int i = q >> 1, h = q & 1;
    float sum = 0.f;
    for (int m = 0; m < H; ++m) sum += Wq[i * 256 + h * 128 + m] * ksum[h * 128 + m];
    u[i * 2 + h] = sum * inv;
  }
  if (t < 2) {
    float sum = 0.f;
    for (int m = 0; m < H; ++m) sum += bq[t * 128 + m] * ksum[t * 128 + m];
    u0[t] = sum * inv + NF;
  }
}

// ---------------- K4: attention apply + residual + LN -> x1 (in-place in ht) ----------------
__global__ __launch_bounds__(256) void k4_attn(float* __restrict__ ht,
    const float* __restrict__ Bc, const float* __restrict__ cc,
    const float* __restrict__ u, const float* __restrict__ u0,
    const float* __restrict__ lng, const float* __restrict__ lnb)
{
  __shared__ float ns[32 * 260];    // +4 pad
  __shared__ float mu_s[32], rs_s[32];
  const int t = threadIdx.x;
  const int R0 = blockIdx.x * 32;
  const int r0 = (t >> 5) * 4;
  const int c0 = (t & 31) * 8;      // 0..248 over 256 (head*128 + d)
  float acc[4][8] = {};
  for (int k0 = 0; k0 < H; k0 += 4) {
    float ax[4][4];
#pragma unroll
    for (int r = 0; r < 4; ++r) {
      float4 a4 = ld4(ht + (size_t)(R0 + r0 + r) * H + k0);
      ax[r][0] = a4.x; ax[r][1] = a4.y; ax[r][2] = a4.z; ax[r][3] = a4.w;
    }
#pragma unroll
    for (int kk = 0; kk < 4; ++kk) {
      float4 b0 = ld4(Bc + (size_t)(k0 + kk) * 256 + c0);
      float4 b1 = ld4(Bc + (size_t)(k0 + kk) * 256 + c0 + 4);
#pragma unroll
      for (int r = 0; r < 4; ++r) {
        float av = ax[r][kk];
        acc[r][0] += av * b0.x; acc[r][1] += av * b0.y;
        acc[r][2] += av * b0.z; acc[r][3] += av * b0.w;
        acc[r][4] += av * b1.x; acc[r][5] += av * b1.y;
        acc[r][6] += av * b1.z; acc[r][7] += av * b1.w;
      }
    }
  }
  const int head = c0 >> 7;
  const float u00 = u0[head];
#pragma unroll
  for (int r = 0; r < 4; ++r) {
    float den = u00;
    const float* hp = ht + (size_t)(R0 + r0 + r) * H;
    for (int k = 0; k < H; k += 4) {
      float4 a4 = ld4(hp + k);
      den += a4.x * u[k * 2 + head] + a4.y * u[(k + 1) * 2 + head]
           + a4.z * u[(k + 2) * 2 + head] + a4.w * u[(k + 3) * 2 + head];
    }
    float rden = 0.5f / den;
#pragma unroll
    for (int j = 0; j < 8; ++j)
      ns[(r0 + r) * 260 + c0 + j] = (acc[r][j] + cc[c0 + j]) * rden;
  }
  __syncthreads();
  const int d0 = (t & 15) * 8;
  const int rr0 = (t >> 4) * 2;
#pragma unroll
  for (int rr = 0; rr < 2; ++rr) {
    const int r = rr0 + rr;
#pragma unroll
    for (int j = 0; j < 8; ++j) {
      const int d = d0 + j;
      float attn = ns[r * 260 + d] + ns[r * 260 + 128 + d];  // mean/2 already folded
      float hm = (attn + ht[(size_t)(R0 + r) * H + d]) * 0.5f;
      ns[r * 260 + d] = hm;          // owner-exclusive slot: safe in-place
    }
  }
  __syncthreads();
  if (t < 32) {
    float sum = 0.f, sq = 0.f;
    for (int c2 = 0; c2 < H; ++c2) {
      float v = ns[t * 260 + c2];
      sum += v; sq += v * v;
    }
    float mu = sum * (1.f / H);
    float var = sq * (1.f / H) - mu * mu;
    mu_s[t] = mu; rs_s[t] = rsqrtf(var + EPS);
  }
  __syncthreads();
#pragma unroll
  for (int rr = 0; rr < 2; ++rr) {
    const int r = rr0 + rr;
    float mu = mu_s[r], rs = rs_s[r];
    float o[8];
#pragma unroll
    for (int j = 0; j < 8; ++j) {
      const int d = d0 + j;
      float v = (ns[r * 260 + d] - mu) * rs * lng[d] + lnb[d];
      o[j] = v > 0.f ? v : 0.f;
    }
    st4(ht + (size_t)(R0 + r) * H + d0, make_float4(o[0], o[1], o[2], o[3]));
    st4(ht + (size_t)(R0 + r) * H + d0 + 4, make_float4(o[4], o[5], o[6], o[7]));
  }
}

// ---------------- K5: in-degree (int counts) ----------------
__global__ __launch_bounds__(256) void k5_deg(const int* __restrict__ ei,
                                              int* __restrict__ cnt)
{
  const int i = blockIdx.x * 256 + threadIdx.x;
  if (i < E) atomicAdd(&cnt[ei[E + i]], 1);
}

// ---------------- scan1: per-1024-chunk sums ----------------
__global__ __launch_bounds__(256) void k_scan1(const int* __restrict__ cnt,
                                               int* __restrict__ bsum)
{
  __shared__ int red[256];
  const int t = threadIdx.x;
  const int base = blockIdx.x * 1024 + t * 4;
  int s = 0;
#pragma unroll
  for (int j = 0; j < 4; ++j) {
    int idx = base + j;
    if (idx < N) s += cnt[idx];
  }
  red[t] = s;
  __syncthreads();
  for (int off = 128; off > 0; off >>= 1) {
    if (t < off) red[t] += red[t + off];
    __syncthreads();
  }
  if (t == 0) bsum[blockIdx.x] = red[0];
}

// ---------------- scan2: serial exclusive scan of 98 block sums ----------------
__global__ void k_scan2(int* __restrict__ bsum)
{
  if (threadIdx.x == 0 && blockIdx.x == 0) {
    int run = 0;
    for (int b = 0; b < NB1024; ++b) {
      int v = bsum[b];
      bsum[b] = run;
      run += v;
    }
  }
}

// ---------------- scan3: intra-chunk exclusive scan -> ptr, cur ----------------
__global__ __launch_bounds__(256) void k_scan3(const int* __restrict__ cnt,
    const int* __restrict__ bsum, int* __restrict__ ptr, int* __restrict__ cur)
{
  __shared__ int part[256];
  const int t = threadIdx.x;
  const int base = blockIdx.x * 1024 + t * 4;
  int v[4];
  int tsum = 0;
#pragma unroll
  for (int j = 0; j < 4; ++j) {
    int idx = base + j;
    v[j] = (idx < N) ? cnt[idx] : 0;
    tsum += v[j];
  }
  part[t] = tsum;
  __syncthreads();
  for (int off = 1; off < 256; off <<= 1) {
    int add = (t >= off) ? part[t - off] : 0;
    __syncthreads();
    part[t] += add;
    __syncthreads();
  }
  int run = bsum[blockIdx.x] + part[t] - tsum;
#pragma unroll
  for (int j = 0; j < 4; ++j) {
    int idx = base + j;
    if (idx < N) { ptr[idx] = run; cur[idx] = run; }
    run += v[j];
  }
}

// ---------------- K6a: place edges into destination buckets ----------------
__global__ __launch_bounds__(256) void k6a_place(const int* __restrict__ ei,
    const int* __restrict__ cnt, int* __restrict__ cur,
    int* __restrict__ srow, float* __restrict__ sval)
{
  const int e = blockIdx.x * 256 + threadIdx.x;
  if (e >= E) return;
  const int r = ei[e];
  const int c = ei[E + e];
  const int p = atomicAdd(&cur[c], 1);
  srow[p] = r;
  const int dr = cnt[r];
  const float dv = (float)dr * (float)cnt[c];
  sval[p] = (dr > 0) ? rsqrtf(dv) : 0.f;   // nan_to_num(inf)=0 when deg[row]==0
}

// ---------------- K6b: gather-accumulate agg[n] = sum val*hg[row] ----------------
__global__ __launch_bounds__(256) void k6b_gather(const int* __restrict__ ptr,
    const int* __restrict__ cnt, const int* __restrict__ srow,
    const float* __restrict__ sval, const float* __restrict__ hg,
    float* __restrict__ agg)
{
  const int t = threadIdx.x;
  const int n = blockIdx.x * 8 + (t >> 5);     // 8 nodes per block
  const int lane4 = (t & 31) * 4;
  const int start = ptr[n];
  const int end = start + cnt[n];
  float4 acc = make_float4(0.f, 0.f, 0.f, 0.f);
  int e = start;
  for (; e + 1 < end; e += 2) {
    int r0 = srow[e], r1 = srow[e + 1];
    float v0 = sval[e], v1 = sval[e + 1];
    float4 h0 = ld4(hg + (size_t)r0 * H + lane4);
    float4 h1 = ld4(hg + (size_t)r1 * H + lane4);
    acc.x += v0 * h0.x + v1 * h1.x;
    acc.y += v0 * h0.y + v1 * h1.y;
    acc.z += v0 * h0.z + v1 * h1.z;
    acc.w += v0 * h0.w + v1 * h1.w;
  }
  if (e < end) {
    int r0 = srow[e];
    float v0 = sval[e];
    float4 h0 = ld4(hg + (size_t)r0 * H + lane4);
    acc.x += v0 * h0.x;
    acc.y += v0 * h0.y;
    acc.z += v0 * h0.z;
    acc.w += v0 * h0.w;
  }
  st4(agg + (size_t)n * H + lane4, acc);
}

// ---------------- K7: conv GEMM + BN + relu + residual -> x2 (in-place in hg) ----------------
__global__ __launch_bounds__(256) void k7_conv(const float* __restrict__ agg,
    float* __restrict__ hg, const float* __restrict__ Wc,
    const float* __restrict__ cb, const float* __restrict__ g1,
    const float* __restrict__ b1)
{
  const int t = threadIdx.x;
  const int R0 = blockIdx.x * 32;
  const int r0 = (t >> 5) * 4;
  const int c0 = (t & 31) * 4;
  float acc[4][4] = {};
  for (int k0 = 0; k0 < H; k0 += 4) {
    float ax[4][4];
#pragma unroll
    for (int r = 0; r < 4; ++r) {
      float4 a4 = ld4(agg + (size_t)(R0 + r0 + r) * H + k0);
      ax[r][0] = a4.x; ax[r][1] = a4.y; ax[r][2] = a4.z; ax[r][3] = a4.w;
    }
#pragma unroll
    for (int kk = 0; kk < 4; ++kk) {
      float4 w = ld4(Wc + (size_t)(k0 + kk) * H + c0);
#pragma unroll
      for (int r = 0; r < 4; ++r) {
        float av = ax[r][kk];
        acc[r][0] += av * w.x; acc[r][1] += av * w.y;
        acc[r][2] += av * w.z; acc[r][3] += av * w.w;
      }
    }
  }
#pragma unroll
  for (int r = 0; r < 4; ++r) {
    size_t off = (size_t)(R0 + r0 + r) * H + c0;
    float4 res = ld4(hg + off);
    float rsv[4] = {res.x, res.y, res.z, res.w};
    float o[4];
#pragma unroll
    for (int j = 0; j < 4; ++j) {
      float v = (acc[r][j] + cb[c0 + j]) * IBN * g1[c0 + j] + b1[c0 + j];
      v = v > 0.f ? v : 0.f;
      o[j] = v + rsv[j];
    }
    st4(hg + off, make_float4(o[0], o[1], o[2], o[3]));
  }
}

// ---------------- K8: out = (0.8*x2 + 0.2*x1) @ fc_w + fc_b ----------------
__global__ __launch_bounds__(256) void k8_out(const float* __restrict__ ht,
    const float* __restrict__ hg, const float* __restrict__ W,
    const float* __restrict__ bias, float* __restrict__ out)
{
  const int t = threadIdx.x;
  const int R0 = blockIdx.x * 32;
  const int rr0 = (t >> 4) * 2;
  const int c0 = (t & 15) * 4;
  float acc[2][4] = {};
  for (int k0 = 0; k0 < H; k0 += 4) {
    float ax[2][4];
#pragma unroll
    for (int r = 0; r < 2; ++r) {
      size_t off = (size_t)(R0 + rr0 + r) * H + k0;
      float4 a1 = ld4(ht + off);
      float4 a2 = ld4(hg + off);
      ax[r][0] = 0.2f * a1.x + 0.8f * a2.x;
      ax[r][1] = 0.2f * a1.y + 0.8f * a2.y;
      ax[r][2] = 0.2f * a1.z + 0.8f * a2.z;
      ax[r][3] = 0.2f * a1.w + 0.8f * a2.w;
    }
#pragma unroll
    for (int kk = 0; kk < 4; ++kk) {
      float4 w = ld4(W + (size_t)(k0 + kk) * C + c0);
#pragma unroll
      for (int r = 0; r < 2; ++r) {
        float av = ax[r][kk];
        acc[r][0] += av * w.x; acc[r][1] += av * w.y;
        acc[r][2] += av * w.z; acc[r][3] += av * w.w;
      }
    }
  }
#pragma unroll
  for (int r = 0; r < 2; ++r) {
    float o[4];
#pragma unroll
    for (int j = 0; j < 4; ++j) o[j] = acc[r][j] + bias[c0 + j];
    st4(out + (size_t)(R0 + rr0 + r) * C + c0, make_float4(o[0], o[1], o[2], o[3]));
  }
}

// ---------------- launch ----------------
extern "C" void kernel_launch(void* const* d_in, const int* in_sizes, int n_in,
                              void* d_out, int out_size, void* d_ws, size_t ws_size,
                              hipStream_t stream) {
  (void)in_sizes; (void)n_in; (void)out_size; (void)ws_size;
  const float* x       = (const float*)d_in[0];
  const int*   ei      = (const int*)d_in[1];
  const float* t_fc_w  = (const float*)d_in[2];
  const float* t_fc_b  = (const float*)d_in[3];
  const float* t_ln0_g = (const float*)d_in[4];
  const float* t_ln0_b = (const float*)d_in[5];
  const float* t_wq_w  = (const float*)d_in[6];
  const float* t_wq_b  = (const float*)d_in[7];
  const float* t_wk_w  = (const float*)d_in[8];
  const float* t_wk_b  = (const float*)d_in[9];
  const float* t_wv_w  = (const float*)d_in[10];
  const float* t_wv_b  = (const float*)d_in[11];
  const float* t_ln1_g = (const float*)d_in[12];
  const float* t_ln1_b = (const float*)d_in[13];
  const float* g_fc_w  = (const float*)d_in[14];
  const float* g_fc_b  = (const float*)d_in[15];
  const float* g_bn0_g = (const float*)d_in[16];
  const float* g_bn0_b = (const float*)d_in[17];
  const float* g_cv_w  = (const float*)d_in[18];
  const float* g_cv_b  = (const float*)d_in[19];
  const float* g_bn1_g = (const float*)d_in[20];
  const float* g_bn1_b = (const float*)d_in[21];
  const float* fc_w    = (const float*)d_in[22];
  const float* fc_b    = (const float*)d_in[23];

  float* W    = (float*)d_ws;
  float* ht   = W + OFF_HT;
  float* hg   = W + OFF_HG;
  float* agg  = W + OFF_AGG;       // first: gram partials; then: gather output
  int*   cnt  = (int*)(W + OFF_CNT);
  float* s    = W + OFF_S;
  float* G    = W + OFF_G;
  int*   ptr  = (int*)(W + OFF_PTR);
  int*   cur  = (int*)(W + OFF_CUR);
  int*   bsum = (int*)(W + OFF_BS);
  int*   srow = (int*)(W + OFF_SROW);
  float* sval = W + OFF_SVAL;
  float* gw   = W + OFF_GWV;
  float* kv   = W + OFF_KV;
  float* ksum = W + OFF_KSUM;
  float* vsum = W + OFF_VSUM;
  float* qsum = W + OFF_QSUM;
  float* sc   = W + OFF_SC;
  float* Bc   = W + OFF_B;
  float* cc   = W + OFF_CC;
  float* u    = W + OFF_U;
  float* u0   = W + OFF_U0;
  unsigned short* Bt = (unsigned short*)(W + OFF_BT);

  hipMemsetAsync(cnt, 0, N * sizeof(int), stream);

  // weight pack for MFMA k1
  k0_cvt<<<512, 256, 0, stream>>>(t_fc_w, g_fc_w, Bt);

  // graph branch CSR build (independent of k1)
  k5_deg<<<(E + 255) / 256, 256, 0, stream>>>(ei, cnt);
  k_scan1<<<NB1024, 256, 0, stream>>>(cnt, bsum);
  k_scan2<<<1, 64, 0, stream>>>(bsum);
  k_scan3<<<NB1024, 256, 0, stream>>>(cnt, bsum, ptr, cur);
  k6a_place<<<E / 256, 256, 0, stream>>>(ei, cnt, cur, srow, sval);

  k1_mfma<<<(N + 63) / 64, 256, 0, stream>>>(x, Bt, t_fc_b, t_ln0_g, t_ln0_b,
                                             g_fc_b, g_bn0_g, g_bn0_b, ht, hg);
  // trans reductions FIRST (partials live in agg, freed before gather overwrites)
  k2_gram<<<NB_GRAM, 256, 0, stream>>>(ht, agg, agg + SP_BASE);
  k2r_reduce<<<64, 256, 0, stream>>>(agg, agg + SP_BASE, G, s);
  // graph aggregation (gather) — overwrites agg
  k6b_gather<<<N / 8, 256, 0, stream>>>(ptr, cnt, srow, sval, hg, agg);
  k3a_gw<<<384, 256, 0, stream>>>(G, t_wv_w, t_wk_w, t_wq_w, gw);
  k3k_sums<<<3, 256, 0, stream>>>(s, t_wk_w, t_wk_b, t_wv_w, t_wv_b, t_wq_w, t_wq_b,
                                  ksum, vsum, qsum);
  k3b_kv<<<128, 256, 0, stream>>>(gw, s, t_wk_w, t_wk_b, t_wv_b, vsum, kv);
  k3c_ssq<<<1, 256, 0, stream>>>(t_wk_w, gw + 32768, t_wq_w, gw + 65536,
                                 t_wk_b, ksum, t_wq_b, qsum, sc);
  k3d_B<<<128, 256, 0, stream>>>(t_wq_w, kv, t_wv_w, sc, Bc);
  k3e_small<<<1, 512, 0, stream>>>(t_wq_b, kv, t_wv_b, t_wq_w, ksum, sc, cc, u, u0);
  k4_attn<<<N / 32, 256, 0, stream>>>(ht, Bc, cc, u, u0, t_ln1_g, t_ln1_b);
  // graph tail + output
  k7_conv<<<N / 32, 256, 0, stream>>>(agg, hg, g_cv_w, g_cv_b, g_bn1_g, g_bn1_b);
  k8_out<<<N / 32, 256, 0, stream>>>(ht, hg, fc_w, fc_b, (float*)d_out);
}

// Round 6
// 1213.062 us; speedup vs baseline: 1.4572x; 1.1051x over previous
//
#include <hip/hip_runtime.h>

// ---------------- problem constants ----------------
constexpr int N = 100000;
constexpr int F = 512;
constexpr int H = 128;
constexpr int E = 1600000;
constexpr int C = 64;
constexpr float EPS = 1e-5f;
constexpr float NF = 100000.0f;     // number of nodes as float
constexpr float IBN = 0.999995000037f; // 1/sqrt(1+1e-5)

// ---------------- workspace layout (float offsets) ----------------
constexpr size_t OFF_HT   = 0;                     // [N,H] trans hidden, later x1 (in-place)
constexpr size_t OFF_HG   = 12800000;              // [N,H] graph hidden, later x2 (in-place)
constexpr size_t OFF_AGG  = 25600000;              // [N,H]; FIRST reused as gram partials, THEN gather output
constexpr size_t OFF_CNT  = 38400000;              // int[N] in-degree  (zeroed)
constexpr size_t OFF_S    = 38500000;              // [128] colsum (written by k2r)
constexpr size_t OFF_G    = 38500128;              // [128,128] gram (written by k2r)
constexpr size_t OFF_PTR  = 38516512;              // int[N] CSR bucket starts
constexpr size_t OFF_CUR  = 38616512;              // int[N] placement cursors
constexpr size_t OFF_BS   = 38716512;              // int[128] scan block offsets
constexpr size_t OFF_SROW = 38716640;              // int[E] sorted src rows
constexpr size_t OFF_SVAL = 40316640;              // float[E] sorted edge weights
constexpr size_t OFF_GWV  = 41916640;              // 3 x [128,256]: G@Wv, G@Wk, G@Wq
constexpr size_t OFF_KV   = OFF_GWV + 3 * 32768;   // [2,128,128] kv_raw
constexpr size_t OFF_KSUM = OFF_KV + 32768;        // [256]
constexpr size_t OFF_VSUM = OFF_KSUM + 256;        // [256]
constexpr size_t OFF_QSUM = OFF_VSUM + 256;        // [256]
constexpr size_t OFF_SC   = OFF_QSUM + 256;        // [4]
constexpr size_t OFF_B    = OFF_SC + 4;            // bf16 Bt2[256][128] (16384 floats used of 32768)
constexpr size_t OFF_CC   = OFF_B + 32768;         // [256]
constexpr size_t OFF_U    = OFF_CC + 256;          // [128,2]
constexpr size_t OFF_U0   = OFF_U + 256;           // [2] (+2 pad)
constexpr size_t OFF_BT   = OFF_U0 + 4;            // bf16[256][512] = 65536 floats

constexpr int NB1024 = (N + 1023) / 1024;          // 98 scan blocks
constexpr int NB_GRAM = (N + 255) / 256;           // 391 gram blocks
constexpr size_t SP_BASE = (size_t)NB_GRAM * 16384; // colsum partials offset inside agg

typedef __attribute__((ext_vector_type(8))) short short8;
typedef __attribute__((ext_vector_type(4))) float floatx4;

__device__ __forceinline__ float4 ld4(const float* p) {
  return *reinterpret_cast<const float4*>(p);
}
__device__ __forceinline__ void st4(float* p, float4 v) {
  *reinterpret_cast<float4*>(p) = v;
}
__device__ __forceinline__ unsigned short f2bf(float f) {
  unsigned u = __float_as_uint(f);
  u += 0x7fff + ((u >> 16) & 1);       // RNE
  return (unsigned short)(u >> 16);
}
__device__ __forceinline__ float bf2f(unsigned short h) {
  return __uint_as_float((unsigned)h << 16);
}

// ---------------- K0: pack Wt||Wg -> bf16 Bt[n=256][k=512] ----------------
__global__ __launch_bounds__(256) void k0_cvt(const float* __restrict__ Wt,
    const float* __restrict__ Wg, unsigned short* __restrict__ Bt)
{
  const int idx = blockIdx.x * 256 + threadIdx.x;   // < 131072
  const int k = idx >> 8;       // 0..511
  const int n = idx & 255;      // 0..255
  float v = (n < 128) ? Wt[(size_t)k * H + n] : Wg[(size_t)k * H + (n - 128)];
  Bt[(size_t)n * F + k] = f2bf(v);
}

// ---------------- K1: MFMA fused fc GEMMs, x -> h_t (relu.LN) and h_g (relu.BN) ----------------
__global__ __launch_bounds__(256) void k1_mfma(
    const float* __restrict__ x, const unsigned short* __restrict__ Bt,
    const float* __restrict__ bt, const float* __restrict__ lng, const float* __restrict__ lnb,
    const float* __restrict__ bgv, const float* __restrict__ bng, const float* __restrict__ bnb,
    float* __restrict__ ht, float* __restrict__ hg)
{
  __shared__ __align__(16) union {
    struct { unsigned short A[64 * 72]; unsigned short B[256 * 72]; } st;  // 46080 B
    struct { float lns[64 * 132]; float mu[64]; float rs[64]; } ln;        // 34304 B
  } sm;
  const int t = threadIdx.x;
  const int lane = t & 63;
  const int w = t >> 6;
  const int rq = (w >> 1) * 32;     // wave row base: 0 / 32
  const int cq = (w & 1) * 128;     // wave col base: 0 / 128
  const int g = lane >> 4;          // 0..3
  const int m = lane & 15;
  const int M0 = blockIdx.x * 64;

  floatx4 acc[2][8];
#pragma unroll
  for (int rt = 0; rt < 2; ++rt)
#pragma unroll
    for (int ct = 0; ct < 8; ++ct) acc[rt][ct] = (floatx4){0.f, 0.f, 0.f, 0.f};

  const int srow = t >> 2;          // 0..63
  const int scol = (t & 3) * 16;    // 0,16,32,48
  const int grow = (M0 + srow < N) ? (M0 + srow) : (N - 1);
  const float* xp = x + (size_t)grow * F;
  const unsigned short* bsrc = Bt + (size_t)t * F;

  for (int k0 = 0; k0 < F; k0 += 64) {
    // stage A: fp32 -> bf16 -> LDS
#pragma unroll
    for (int j = 0; j < 4; ++j) {
      float4 a4 = ld4(xp + k0 + scol + j * 4);
      ushort4 p;
      p.x = f2bf(a4.x); p.y = f2bf(a4.y); p.z = f2bf(a4.z); p.w = f2bf(a4.w);
      *(ushort4*)(sm.st.A + srow * 72 + scol + j * 4) = p;
    }
    // stage B: n = t, 64 bf16
#pragma unroll
    for (int j = 0; j < 8; ++j)
      *(uint4*)(sm.st.B + t * 72 + j * 8) = *(const uint4*)(bsrc + k0 + j * 8);
    __syncthreads();
#pragma unroll
    for (int kk = 0; kk < 64; kk += 32) {
      short8 af[2], bf[8];
#pragma unroll
      for (int rt = 0; rt < 2; ++rt)
        af[rt] = *(const short8*)(sm.st.A + (rq + rt * 16 + m) * 72 + kk + g * 8);
#pragma unroll
      for (int ct = 0; ct < 8; ++ct)
        bf[ct] = *(const short8*)(sm.st.B + (cq + ct * 16 + m) * 72 + kk + g * 8);
#pragma unroll
      for (int rt = 0; rt < 2; ++rt)
#pragma unroll
        for (int ct = 0; ct < 8; ++ct)
          acc[rt][ct] = __builtin_amdgcn_mfma_f32_16x16x32_bf16(af[rt], bf[ct], acc[rt][ct], 0, 0, 0);
    }
    __syncthreads();
  }
  // epilogue. C/D layout: col = m, row = g*4 + reg
  if (cq == 0) {
#pragma unroll
    for (int rt = 0; rt < 2; ++rt)
#pragma unroll
      for (int ct = 0; ct < 8; ++ct) {
        const int col = ct * 16 + m;
        const float b = bt[col];
#pragma unroll
        for (int r = 0; r < 4; ++r)
          sm.ln.lns[(rq + rt * 16 + g * 4 + r) * 132 + col] = acc[rt][ct][r] + b;
      }
  } else {
#pragma unroll
    for (int rt = 0; rt < 2; ++rt)
#pragma unroll
      for (int ct = 0; ct < 8; ++ct) {
        const int col = ct * 16 + m;
        const float s1 = IBN * bng[col], b0 = bgv[col], b2 = bnb[col];
#pragma unroll
        for (int r = 0; r < 4; ++r) {
          const int row = M0 + rq + rt * 16 + g * 4 + r;
          if (row < N) {
            float v = (acc[rt][ct][r] + b0) * s1 + b2;
            hg[(size_t)row * H + col] = v > 0.f ? v : 0.f;
          }
        }
      }
  }
  __syncthreads();
  if (t < 64) {
    float sum = 0.f, sq = 0.f;
    for (int c2 = 0; c2 < H; ++c2) {
      float v = sm.ln.lns[t * 132 + c2];
      sum += v; sq += v * v;
    }
    float mu = sum * (1.f / H);
    float var = sq * (1.f / H) - mu * mu;
    sm.ln.mu[t] = mu; sm.ln.rs[t] = rsqrtf(var + EPS);
  }
  __syncthreads();
  {
    const int r = t >> 2;
    const int cb = (t & 3) * 32;
    if (M0 + r < N) {
      const float mu = sm.ln.mu[r], rs = sm.ln.rs[r];
#pragma unroll
      for (int j = 0; j < 8; ++j) {
        const int c = cb + j * 4;
        float o[4];
#pragma unroll
        for (int q = 0; q < 4; ++q) {
          float v = (sm.ln.lns[r * 132 + c + q] - mu) * rs * lng[c + q] + lnb[c + q];
          o[q] = v > 0.f ? v : 0.f;
        }
        st4(ht + (size_t)(M0 + r) * H + c, make_float4(o[0], o[1], o[2], o[3]));
      }
    }
  }
}

// ---------------- K2: gram + colsum partials, NO atomics ----------------
__global__ __launch_bounds__(256) void k2_gram(const float* __restrict__ ht,
                                               float* __restrict__ gp,   // [NB_GRAM][16384]
                                               float* __restrict__ sp)   // [NB_GRAM][128]
{
  const int t = threadIdx.x;
  const int b = blockIdx.x;
  const int base = b * 256;
  const int nend = (base + 256 < N) ? base + 256 : N;
  const int r0 = (t >> 4) * 8;
  const int c0 = (t & 15) * 8;
  float acc[8][8] = {};
  float colacc[8] = {};
  const bool do_col = (t < 16);
  int n = base;
  for (; n + 1 < nend; n += 2) {
    const float* hp0 = ht + (size_t)n * H;
    const float* hp1 = hp0 + H;
    float4 a00 = ld4(hp0 + r0), a01 = ld4(hp0 + r0 + 4);
    float4 b00 = ld4(hp0 + c0), b01 = ld4(hp0 + c0 + 4);
    float4 a10 = ld4(hp1 + r0), a11 = ld4(hp1 + r0 + 4);
    float4 b10 = ld4(hp1 + c0), b11 = ld4(hp1 + c0 + 4);
    float a0[8] = {a00.x, a00.y, a00.z, a00.w, a01.x, a01.y, a01.z, a01.w};
    float b0[8] = {b00.x, b00.y, b00.z, b00.w, b01.x, b01.y, b01.z, b01.w};
    float a1[8] = {a10.x, a10.y, a10.z, a10.w, a11.x, a11.y, a11.z, a11.w};
    float b1[8] = {b10.x, b10.y, b10.z, b10.w, b11.x, b11.y, b11.z, b11.w};
    if (do_col) {
#pragma unroll
      for (int j = 0; j < 8; ++j) colacc[j] += b0[j] + b1[j];
    }
#pragma unroll
    for (int i = 0; i < 8; ++i)
#pragma unroll
      for (int j = 0; j < 8; ++j)
        acc[i][j] += a0[i] * b0[j] + a1[i] * b1[j];
  }
  if (n < nend) {
    const float* hp0 = ht + (size_t)n * H;
    float4 a00 = ld4(hp0 + r0), a01 = ld4(hp0 + r0 + 4);
    float4 b00 = ld4(hp0 + c0), b01 = ld4(hp0 + c0 + 4);
    float a0[8] = {a00.x, a00.y, a00.z, a00.w, a01.x, a01.y, a01.z, a01.w};
    float b0[8] = {b00.x, b00.y, b00.z, b00.w, b01.x, b01.y, b01.z, b01.w};
    if (do_col) {
#pragma unroll
      for (int j = 0; j < 8; ++j) colacc[j] += b0[j];
    }
#pragma unroll
    for (int i = 0; i < 8; ++i)
#pragma unroll
      for (int j = 0; j < 8; ++j)
        acc[i][j] += a0[i] * b0[j];
  }
  float* g = gp + (size_t)b * 16384;
#pragma unroll
  for (int i = 0; i < 8; ++i) {
    st4(&g[(r0 + i) * H + c0], make_float4(acc[i][0], acc[i][1], acc[i][2], acc[i][3]));
    st4(&g[(r0 + i) * H + c0 + 4], make_float4(acc[i][4], acc[i][5], acc[i][6], acc[i][7]));
  }
  if (do_col) {
    float* spb = sp + (size_t)b * 128;
    st4(&spb[c0], make_float4(colacc[0], colacc[1], colacc[2], colacc[3]));
    st4(&spb[c0 + 4], make_float4(colacc[4], colacc[5], colacc[6], colacc[7]));
  }
}

// ---------------- K2r: reduce partials -> G, s ----------------
__global__ __launch_bounds__(256) void k2r_reduce(const float* __restrict__ gp,
    const float* __restrict__ sp, float* __restrict__ G, float* __restrict__ s)
{
  const int i = blockIdx.x * 256 + threadIdx.x;   // < 16384
  float s0 = 0.f, s1 = 0.f, s2 = 0.f, s3 = 0.f;
  int b = 0;
  for (; b + 3 < NB_GRAM; b += 4) {
    s0 += gp[(size_t)b * 16384 + i];
    s1 += gp[(size_t)(b + 1) * 16384 + i];
    s2 += gp[(size_t)(b + 2) * 16384 + i];
    s3 += gp[(size_t)(b + 3) * 16384 + i];
  }
  for (; b < NB_GRAM; ++b) s0 += gp[(size_t)b * 16384 + i];
  G[i] = (s0 + s1) + (s2 + s3);
  if (blockIdx.x == 0 && threadIdx.x < 128) {
    float t0 = 0.f, t1 = 0.f;
    int bb = 0;
    for (; bb + 1 < NB_GRAM; bb += 2) {
      t0 += sp[(size_t)bb * 128 + threadIdx.x];
      t1 += sp[(size_t)(bb + 1) * 128 + threadIdx.x];
    }
    for (; bb < NB_GRAM; ++bb) t0 += sp[(size_t)bb * 128 + threadIdx.x];
    s[threadIdx.x] = t0 + t1;
  }
}

// ---------------- K3a: GW = G @ {Wv, Wk, Wq} ----------------
__global__ __launch_bounds__(256) void k3a_gw(const float* __restrict__ G,
    const float* __restrict__ Wv, const float* __restrict__ Wk,
    const float* __restrict__ Wq, float* __restrict__ GW)
{
  const int flat = blockIdx.x * 256 + threadIdx.x;   // < 98304
  const int w = flat >> 15;
  const int rem = flat & 32767;
  const int i = rem >> 8;
  const int j = rem & 255;
  const float* W = (w == 0) ? Wv : (w == 1) ? Wk : Wq;
  float sum = 0.f;
#pragma unroll 8
  for (int k = 0; k < H; ++k) sum += G[i * H + k] * W[k * 256 + j];
  GW[flat] = sum;
}

// ---------------- K3k: ksum/vsum/qsum = s @ W + N*b ----------------
__global__ __launch_bounds__(256) void k3k_sums(const float* __restrict__ s,
    const float* __restrict__ Wk, const float* __restrict__ bk,
    const float* __restrict__ Wv, const float* __restrict__ bv,
    const float* __restrict__ Wq, const float* __restrict__ bq,
    float* __restrict__ ksum, float* __restrict__ vsum, float* __restrict__ qsum)
{
  const int flat = blockIdx.x * 256 + threadIdx.x;   // < 768
  const int w = flat >> 8;
  const int j = flat & 255;
  const float* W = (w == 0) ? Wk : (w == 1) ? Wv : Wq;
  const float* b = (w == 0) ? bk : (w == 1) ? bv : bq;
  float* out = (w == 0) ? ksum : (w == 1) ? vsum : qsum;
  float sum = 0.f;
#pragma unroll 8
  for (int k = 0; k < H; ++k) sum += s[k] * W[k * 256 + j];
  out[j] = sum + NF * b[j];
}

// ---------------- K3b: kv_raw[h,m,d] ----------------
__global__ __launch_bounds__(256) void k3b_kv(const float* __restrict__ GWv,
    const float* __restrict__ s, const float* __restrict__ Wk,
    const float* __restrict__ bk, const float* __restrict__ bv,
    const float* __restrict__ vsum, float* __restrict__ kv)
{
  const int flat = blockIdx.x * 256 + threadIdx.x;   // < 32768
  const int h = flat >> 14;
  const int m = (flat >> 7) & 127;
  const int d = flat & 127;
  float s1 = 0.f, s2 = 0.f;
#pragma unroll 4
  for (int k = 0; k < H; ++k) {
    float wkv = Wk[k * 256 + h * 128 + m];
    s1 += wkv * GWv[k * 256 + h * 128 + d];
    s2 += wkv * s[k];
  }
  kv[flat] = s1 + s2 * bv[h * 128 + d] + bk[h * 128 + m] * vsum[h * 128 + d];
}

// ---------------- K3c: ssq_q, ssq_k, inv ----------------
__global__ __launch_bounds__(256) void k3c_ssq(
    const float* __restrict__ Wk, const float* __restrict__ GWk,
    const float* __restrict__ Wq, const float* __restrict__ GWq,
    const float* __restrict__ bk, const float* __restrict__ ksum,
    const float* __restrict__ bq, const float* __restrict__ qsum,
    float* __restrict__ sc)
{
  __shared__ float red[512];
  const int t = threadIdx.x;
  float pk = 0.f, pq = 0.f;
  for (int i = t; i < 32768; i += 256) {
    pk += Wk[i] * GWk[i];
    pq += Wq[i] * GWq[i];
  }
  pk += 2.f * bk[t] * ksum[t] - NF * bk[t] * bk[t];
  pq += 2.f * bq[t] * qsum[t] - NF * bq[t] * bq[t];
  red[t] = pk; red[256 + t] = pq;
  __syncthreads();
  for (int off = 128; off > 0; off >>= 1) {
    if (t < off) { red[t] += red[t + off]; red[256 + t] += red[256 + t + off]; }
    __syncthreads();
  }
  if (t == 0) {
    float ssq_k = red[0], ssq_q = red[256];
    sc[0] = ssq_q; sc[1] = ssq_k;
    sc[2] = rsqrtf(ssq_q * ssq_k);   // 1/(||q|| * ||k||)
  }
}

// ---------------- K3d: B = Wq @ kv * inv + N*Wv -> packed bf16 Bt2[n=256][k=128] ----------------
__global__ __launch_bounds__(256) void k3d_B(const float* __restrict__ Wq,
    const float* __restrict__ kv, const float* __restrict__ Wv,
    const float* __restrict__ sc, unsigned short* __restrict__ Bt2)
{
  const int flat = blockIdx.x * 256 + threadIdx.x;   // < 32768
  const int i = flat >> 8;       // 0..127 : k-dim (h index)
  const int j = flat & 255;      // 0..255 : col (head*128 + d)
  const int h = j >> 7;
  const int d = j & 127;
  const float inv = sc[2];
  float sum = 0.f;
#pragma unroll 4
  for (int m = 0; m < H; ++m)
    sum += Wq[i * 256 + h * 128 + m] * kv[h * 16384 + m * 128 + d];
  Bt2[(size_t)j * H + i] = f2bf(sum * inv + NF * Wv[i * 256 + j]);
}

// ---------------- K3e: c, u, u0 ----------------
__global__ __launch_bounds__(512) void k3e_small(const float* __restrict__ bq,
    const float* __restrict__ kv, const float* __restrict__ bv,
    const float* __restrict__ Wq, const float* __restrict__ ksum,
    const float* __restrict__ sc, float* __restrict__ cc,
    float* __restrict__ u, float* __restrict__ u0)
{
  const int t = threadIdx.x;
  const float inv = sc[2];
  if (t < 256) {
    const int h = t >> 7, d = t & 127;
    float sum = 0.f;
    for (int m = 0; m < H; ++m) sum += bq[h * 128 + m] * kv[h * 16384 + m * 128 + d];
    cc[t] = sum * inv + NF * bv[t];
  } else {
    const int q = t - 256;
    const int i = q >> 1, h = q & 1;
    float sum = 0.f;
    for (int m = 0; m < H; ++m) sum += Wq[i * 256 + h * 128 + m] * ksum[h * 128 + m];
    u[i * 2 + h] = sum * inv;
  }
  if (t < 2) {
    float sum = 0.f;
    for (int m = 0; m < H; ++m) sum += bq[t * 128 + m] * ksum[t * 128 + m];
    u0[t] = sum * inv + NF;
  }
}

// ---------------- K4: MFMA attention apply + residual + LN -> x1 (in-place in ht) ----------------
// 64-row tile; 4 waves; each wave: 16 rows x all 256 cols (head combine is in-lane: ct vs ct+8)
__global__ __launch_bounds__(256) void k4_mfma(float* __restrict__ ht,
    const unsigned short* __restrict__ Bt2, const float* __restrict__ cc,
    const float* __restrict__ u, const float* __restrict__ u0,
    const float* __restrict__ lng, const float* __restrict__ lnb)
{
  __shared__ __align__(16) union {
    unsigned short A[64 * 136];       // 17408 B (bf16 ht tile)
    float lns[64 * 132];              // 33792 B (LN staging)
  } sm;
  __shared__ float u_s[256];
  __shared__ float rden_s[128];       // [row][head]
  __shared__ float mu_s[64], rs_s[64];
  const int t = threadIdx.x;
  const int lane = t & 63;
  const int w = t >> 6;
  const int rq = w * 16;              // wave row base 0/16/32/48
  const int g = lane >> 4;
  const int m = lane & 15;
  const int M0 = blockIdx.x * 64;

  // stage A: ht rows fp32 -> bf16 LDS (K=128 fits entirely)
  {
    const int srow = t >> 2;          // 0..63
    const int scol = (t & 3) * 32;    // 0,32,64,96
    const int grow = (M0 + srow < N) ? (M0 + srow) : (N - 1);
    const float* xp = ht + (size_t)grow * H + scol;
#pragma unroll
    for (int j = 0; j < 8; ++j) {
      float4 a4 = ld4(xp + j * 4);
      ushort4 p;
      p.x = f2bf(a4.x); p.y = f2bf(a4.y); p.z = f2bf(a4.z); p.w = f2bf(a4.w);
      *(ushort4*)(sm.A + srow * 136 + scol + j * 4) = p;
    }
  }
  u_s[t] = u[t];
  __syncthreads();

  floatx4 acc[16];
#pragma unroll
  for (int ct = 0; ct < 16; ++ct) acc[ct] = (floatx4){0.f, 0.f, 0.f, 0.f};
#pragma unroll
  for (int kk = 0; kk < 128; kk += 32) {
    short8 af = *(const short8*)(sm.A + (rq + m) * 136 + kk + g * 8);
#pragma unroll
    for (int ct = 0; ct < 16; ++ct) {
      short8 bf = *(const short8*)(Bt2 + (size_t)(ct * 16 + m) * H + kk + g * 8);
      acc[ct] = __builtin_amdgcn_mfma_f32_16x16x32_bf16(af, bf, acc[ct], 0, 0, 0);
    }
  }
  // denominators (waves 0,1): row=t>>1, head=t&1
  if (t < 128) {
    const int row = t >> 1, head = t & 1;
    float den = u0[head];
    for (int k = 0; k < H; ++k)
      den += bf2f(sm.A[row * 136 + k]) * u_s[k * 2 + head];
    rden_s[row * 2 + head] = 0.5f / den;   // mean-over-heads folded
  }
  __syncthreads();   // A fully consumed; lns may now overwrite the union

  // combine heads + residual -> lns
#pragma unroll
  for (int ct = 0; ct < 8; ++ct) {
    const int d = ct * 16 + m;
    const float c0v = cc[d], c1v = cc[128 + d];
#pragma unroll
    for (int r = 0; r < 4; ++r) {
      const int row = rq + g * 4 + r;         // block-local 0..63
      const int grow = M0 + row;
      const float rd0 = rden_s[row * 2], rd1 = rden_s[row * 2 + 1];
      float attn = (acc[ct][r] + c0v) * rd0 + (acc[ct + 8][r] + c1v) * rd1;
      float hres = (grow < N) ? ht[(size_t)grow * H + d] : 0.f;
      sm.lns[row * 132 + d] = (attn + hres) * 0.5f;
    }
  }
  __syncthreads();
  if (t < 64) {
    float sum = 0.f, sq = 0.f;
    for (int c2 = 0; c2 < H; ++c2) {
      float v = sm.lns[t * 132 + c2];
      sum += v; sq += v * v;
    }
    float mu = sum * (1.f / H);
    float var = sq * (1.f / H) - mu * mu;
    mu_s[t] = mu; rs_s[t] = rsqrtf(var + EPS);
  }
  __syncthreads();
  {
    const int r = t >> 2;
    const int cb = (t & 3) * 32;
    if (M0 + r < N) {
      const float mu = mu_s[r], rs = rs_s[r];
#pragma unroll
      for (int j = 0; j < 8; ++j) {
        const int c = cb + j * 4;
        float o[4];
#pragma unroll
        for (int q = 0; q < 4; ++q) {
          float v = (sm.lns[r * 132 + c + q] - mu) * rs * lng[c + q] + lnb[c + q];
          o[q] = v > 0.f ? v : 0.f;
        }
        st4(ht + (size_t)(M0 + r) * H + c, make_float4(o[0], o[1], o[2], o[3]));
      }
    }
  }
}

// ---------------- K5: in-degree (int counts) ----------------
__global__ __launch_bounds__(256) void k5_deg(const int* __restrict__ ei,
                                              int* __restrict__ cnt)
{
  const int i = blockIdx.x * 256 + threadIdx.x;
  if (i < E) atomicAdd(&cnt[ei[E + i]], 1);
}

// ---------------- scan1: per-1024-chunk sums ----------------
__global__ __launch_bounds__(256) void k_scan1(const int* __restrict__ cnt,
                                               int* __restrict__ bsum)
{
  __shared__ int red[256];
  const int t = threadIdx.x;
  const int base = blockIdx.x * 1024 + t * 4;
  int s = 0;
#pragma unroll
  for (int j = 0; j < 4; ++j) {
    int idx = base + j;
    if (idx < N) s += cnt[idx];
  }
  red[t] = s;
  __syncthreads();
  for (int off = 128; off > 0; off >>= 1) {
    if (t < off) red[t] += red[t + off];
    __syncthreads();
  }
  if (t == 0) bsum[blockIdx.x] = red[0];
}

// ---------------- scan2: serial exclusive scan of 98 block sums ----------------
__global__ void k_scan2(int* __restrict__ bsum)
{
  if (threadIdx.x == 0 && blockIdx.x == 0) {
    int run = 0;
    for (int b = 0; b < NB1024; ++b) {
      int v = bsum[b];
      bsum[b] = run;
      run += v;
    }
  }
}

// ---------------- scan3: intra-chunk exclusive scan -> ptr, cur ----------------
__global__ __launch_bounds__(256) void k_scan3(const int* __restrict__ cnt,
    const int* __restrict__ bsum, int* __restrict__ ptr, int* __restrict__ cur)
{
  __shared__ int part[256];
  const int t = threadIdx.x;
  const int base = blockIdx.x * 1024 + t * 4;
  int v[4];
  int tsum = 0;
#pragma unroll
  for (int j = 0; j < 4; ++j) {
    int idx = base + j;
    v[j] = (idx < N) ? cnt[idx] : 0;
    tsum += v[j];
  }
  part[t] = tsum;
  __syncthreads();
  for (int off = 1; off < 256; off <<= 1) {
    int add = (t >= off) ? part[t - off] : 0;
    __syncthreads();
    part[t] += add;
    __syncthreads();
  }
  int run = bsum[blockIdx.x] + part[t] - tsum;
#pragma unroll
  for (int j = 0; j < 4; ++j) {
    int idx = base + j;
    if (idx < N) { ptr[idx] = run; cur[idx] = run; }
    run += v[j];
  }
}

// ---------------- K6a: place edges into destination buckets ----------------
__global__ __launch_bounds__(256) void k6a_place(const int* __restrict__ ei,
    const int* __restrict__ cnt, int* __restrict__ cur,
    int* __restrict__ srow, float* __restrict__ sval)
{
  const int e = blockIdx.x * 256 + threadIdx.x;
  if (e >= E) return;
  const int r = ei[e];
  const int c = ei[E + e];
  const int p = atomicAdd(&cur[c], 1);
  srow[p] = r;
  const int dr = cnt[r];
  const float dv = (float)dr * (float)cnt[c];
  sval[p] = (dr > 0) ? rsqrtf(dv) : 0.f;   // nan_to_num(inf)=0 when deg[row]==0
}

// ---------------- K6b: gather-accumulate agg[n] = sum val*hg[row] ----------------
__global__ __launch_bounds__(256) void k6b_gather(const int* __restrict__ ptr,
    const int* __restrict__ cnt, const int* __restrict__ srow,
    const float* __restrict__ sval, const float* __restrict__ hg,
    float* __restrict__ agg)
{
  const int t = threadIdx.x;
  const int n = blockIdx.x * 8 + (t >> 5);     // 8 nodes per block
  const int lane4 = (t & 31) * 4;
  const int start = ptr[n];
  const int end = start + cnt[n];
  float4 acc = make_float4(0.f, 0.f, 0.f, 0.f);
  int e = start;
  for (; e + 1 < end; e += 2) {
    int r0 = srow[e], r1 = srow[e + 1];
    float v0 = sval[e], v1 = sval[e + 1];
    float4 h0 = ld4(hg + (size_t)r0 * H + lane4);
    float4 h1 = ld4(hg + (size_t)r1 * H + lane4);
    acc.x += v0 * h0.x + v1 * h1.x;
    acc.y += v0 * h0.y + v1 * h1.y;
    acc.z += v0 * h0.z + v1 * h1.z;
    acc.w += v0 * h0.w + v1 * h1.w;
  }
  if (e < end) {
    int r0 = srow[e];
    float v0 = sval[e];
    float4 h0 = ld4(hg + (size_t)r0 * H + lane4);
    acc.x += v0 * h0.x;
    acc.y += v0 * h0.y;
    acc.z += v0 * h0.z;
    acc.w += v0 * h0.w;
  }
  st4(agg + (size_t)n * H + lane4, acc);
}

// ---------------- K7: conv GEMM + BN + relu + residual -> x2 (in-place in hg) ----------------
__global__ __launch_bounds__(256) void k7_conv(const float* __restrict__ agg,
    float* __restrict__ hg, const float* __restrict__ Wc,
    const float* __restrict__ cb, const float* __restrict__ g1,
    const float* __restrict__ b1)
{
  const int t = threadIdx.x;
  const int R0 = blockIdx.x * 32;
  const int r0 = (t >> 5) * 4;
  const int c0 = (t & 31) * 4;
  float acc[4][4] = {};
  for (int k0 = 0; k0 < H; k0 += 4) {
    float ax[4][4];
#pragma unroll
    for (int r = 0; r < 4; ++r) {
      float4 a4 = ld4(agg + (size_t)(R0 + r0 + r) * H + k0);
      ax[r][0] = a4.x; ax[r][1] = a4.y; ax[r][2] = a4.z; ax[r][3] = a4.w;
    }
#pragma unroll
    for (int kk = 0; kk < 4; ++kk) {
      float4 w = ld4(Wc + (size_t)(k0 + kk) * H + c0);
#pragma unroll
      for (int r = 0; r < 4; ++r) {
        float av = ax[r][kk];
        acc[r][0] += av * w.x; acc[r][1] += av * w.y;
        acc[r][2] += av * w.z; acc[r][3] += av * w.w;
      }
    }
  }
#pragma unroll
  for (int r = 0; r < 4; ++r) {
    size_t off = (size_t)(R0 + r0 + r) * H + c0;
    float4 res = ld4(hg + off);
    float rsv[4] = {res.x, res.y, res.z, res.w};
    float o[4];
#pragma unroll
    for (int j = 0; j < 4; ++j) {
      float v = (acc[r][j] + cb[c0 + j]) * IBN * g1[c0 + j] + b1[c0 + j];
      v = v > 0.f ? v : 0.f;
      o[j] = v + rsv[j];
    }
    st4(hg + off, make_float4(o[0], o[1], o[2], o[3]));
  }
}

// ---------------- K8: out = (0.8*x2 + 0.2*x1) @ fc_w + fc_b ----------------
__global__ __launch_bounds__(256) void k8_out(const float* __restrict__ ht,
    const float* __restrict__ hg, const float* __restrict__ W,
    const float* __restrict__ bias, float* __restrict__ out)
{
  const int t = threadIdx.x;
  const int R0 = blockIdx.x * 32;
  const int rr0 = (t >> 4) * 2;
  const int c0 = (t & 15) * 4;
  float acc[2][4] = {};
  for (int k0 = 0; k0 < H; k0 += 4) {
    float ax[2][4];
#pragma unroll
    for (int r = 0; r < 2; ++r) {
      size_t off = (size_t)(R0 + rr0 + r) * H + k0;
      float4 a1 = ld4(ht + off);
      float4 a2 = ld4(hg + off);
      ax[r][0] = 0.2f * a1.x + 0.8f * a2.x;
      ax[r][1] = 0.2f * a1.y + 0.8f * a2.y;
      ax[r][2] = 0.2f * a1.z + 0.8f * a2.z;
      ax[r][3] = 0.2f * a1.w + 0.8f * a2.w;
    }
#pragma unroll
    for (int kk = 0; kk < 4; ++kk) {
      float4 w = ld4(W + (size_t)(k0 + kk) * C + c0);
#pragma unroll
      for (int r = 0; r < 2; ++r) {
        float av = ax[r][kk];
        acc[r][0] += av * w.x; acc[r][1] += av * w.y;
        acc[r][2] += av * w.z; acc[r][3] += av * w.w;
      }
    }
  }
#pragma unroll
  for (int r = 0; r < 2; ++r) {
    float o[4];
#pragma unroll
    for (int j = 0; j < 4; ++j) o[j] = acc[r][j] + bias[c0 + j];
    st4(out + (size_t)(R0 + rr0 + r) * C + c0, make_float4(o[0], o[1], o[2], o[3]));
  }
}

// ---------------- launch ----------------
extern "C" void kernel_launch(void* const* d_in, const int* in_sizes, int n_in,
                              void* d_out, int out_size, void* d_ws, size_t ws_size,
                              hipStream_t stream) {
  (void)in_sizes; (void)n_in; (void)out_size; (void)ws_size;
  const float* x       = (const float*)d_in[0];
  const int*   ei      = (const int*)d_in[1];
  const float* t_fc_w  = (const float*)d_in[2];
  const float* t_fc_b  = (const float*)d_in[3];
  const float* t_ln0_g = (const float*)d_in[4];
  const float* t_ln0_b = (const float*)d_in[5];
  const float* t_wq_w  = (const float*)d_in[6];
  const float* t_wq_b  = (const float*)d_in[7];
  const float* t_wk_w  = (const float*)d_in[8];
  const float* t_wk_b  = (const float*)d_in[9];
  const float* t_wv_w  = (const float*)d_in[10];
  const float* t_wv_b  = (const float*)d_in[11];
  const float* t_ln1_g = (const float*)d_in[12];
  const float* t_ln1_b = (const float*)d_in[13];
  const float* g_fc_w  = (const float*)d_in[14];
  const float* g_fc_b  = (const float*)d_in[15];
  const float* g_bn0_g = (const float*)d_in[16];
  const float* g_bn0_b = (const float*)d_in[17];
  const float* g_cv_w  = (const float*)d_in[18];
  const float* g_cv_b  = (const float*)d_in[19];
  const float* g_bn1_g = (const float*)d_in[20];
  const float* g_bn1_b = (const float*)d_in[21];
  const float* fc_w    = (const float*)d_in[22];
  const float* fc_b    = (const float*)d_in[23];

  float* W    = (float*)d_ws;
  float* ht   = W + OFF_HT;
  float* hg   = W + OFF_HG;
  float* agg  = W + OFF_AGG;       // first: gram partials; then: gather output
  int*   cnt  = (int*)(W + OFF_CNT);
  float* s    = W + OFF_S;
  float* G    = W + OFF_G;
  int*   ptr  = (int*)(W + OFF_PTR);
  int*   cur  = (int*)(W + OFF_CUR);
  int*   bsum = (int*)(W + OFF_BS);
  int*   srow = (int*)(W + OFF_SROW);
  float* sval = W + OFF_SVAL;
  float* gw   = W + OFF_GWV;
  float* kv   = W + OFF_KV;
  float* ksum = W + OFF_KSUM;
  float* vsum = W + OFF_VSUM;
  float* qsum = W + OFF_QSUM;
  float* sc   = W + OFF_SC;
  unsigned short* Bt2 = (unsigned short*)(W + OFF_B);
  float* cc   = W + OFF_CC;
  float* u    = W + OFF_U;
  float* u0   = W + OFF_U0;
  unsigned short* Bt = (unsigned short*)(W + OFF_BT);

  hipMemsetAsync(cnt, 0, N * sizeof(int), stream);

  // weight pack for MFMA k1
  k0_cvt<<<512, 256, 0, stream>>>(t_fc_w, g_fc_w, Bt);

  // graph branch CSR build (independent of k1)
  k5_deg<<<(E + 255) / 256, 256, 0, stream>>>(ei, cnt);
  k_scan1<<<NB1024, 256, 0, stream>>>(cnt, bsum);
  k_scan2<<<1, 64, 0, stream>>>(bsum);
  k_scan3<<<NB1024, 256, 0, stream>>>(cnt, bsum, ptr, cur);
  k6a_place<<<E / 256, 256, 0, stream>>>(ei, cnt, cur, srow, sval);

  k1_mfma<<<(N + 63) / 64, 256, 0, stream>>>(x, Bt, t_fc_b, t_ln0_g, t_ln0_b,
                                             g_fc_b, g_bn0_g, g_bn0_b, ht, hg);
  // trans reductions FIRST (partials live in agg, freed before gather overwrites)
  k2_gram<<<NB_GRAM, 256, 0, stream>>>(ht, agg, agg + SP_BASE);
  k2r_reduce<<<64, 256, 0, stream>>>(agg, agg + SP_BASE, G, s);
  // graph aggregation (gather) — overwrites agg
  k6b_gather<<<N / 8, 256, 0, stream>>>(ptr, cnt, srow, sval, hg, agg);
  k3a_gw<<<384, 256, 0, stream>>>(G, t_wv_w, t_wk_w, t_wq_w, gw);
  k3k_sums<<<3, 256, 0, stream>>>(s, t_wk_w, t_wk_b, t_wv_w, t_wv_b, t_wq_w, t_wq_b,
                                  ksum, vsum, qsum);
  k3b_kv<<<128, 256, 0, stream>>>(gw, s, t_wk_w, t_wk_b, t_wv_b, vsum, kv);
  k3c_ssq<<<1, 256, 0, stream>>>(t_wk_w, gw + 32768, t_wq_w, gw + 65536,
                                 t_wk_b, ksum, t_wq_b, qsum, sc);
  k3d_B<<<128, 256, 0, stream>>>(t_wq_w, kv, t_wv_w, sc, Bt2);
  k3e_small<<<1, 512, 0, stream>>>(t_wq_b, kv, t_wv_b, t_wq_w, ksum, sc, cc, u, u0);
  k4_mfma<<<(N + 63) / 64, 256, 0, stream>>>(ht, Bt2, cc, u, u0, t_ln1_g, t_ln1_b);
  // graph tail + output
  k7_conv<<<N / 32, 256, 0, stream>>>(agg, hg, g_cv_w, g_cv_b, g_bn1_g, g_bn1_b);
  k8_out<<<N / 32, 256, 0, stream>>>(ht, hg, fc_w, fc_b, (float*)d_out);
}